// Round 5
// baseline (171.648 us; speedup 1.0000x reference)
//
#include <hip/hip_runtime.h>
#include <hip/hip_bf16.h>

#define NL 4096   // 64*64 low-res pixels
#define HH 32
#define WH 32

typedef __attribute__((ext_vector_type(8))) short s8v;   // 8 bf16 MFMA A/B frag
typedef __attribute__((ext_vector_type(4))) short s4v;   // 4 bf16 (8B)
typedef __attribute__((ext_vector_type(4))) float f32x4; // MFMA C/D frag
typedef __attribute__((ext_vector_type(8))) float f32x8; // 8 f32 (2x dwordx4)

static __device__ inline unsigned short f2bf(float x) {
  __hip_bfloat16 h = __float2bfloat16(x);   // RNE
  return *reinterpret_cast<unsigned short*>(&h);
}
static __device__ inline float bfbits2f(unsigned int lo16) {
  unsigned int u = lo16 << 16;
  return *reinterpret_cast<float*>(&u);
}
// 8x f32 -> 8x bf16 (compiler emits v_cvt_pk_bf16_f32 pairs)
static __device__ inline s8v cvt8(f32x8 v) {
  s8v o;
#pragma unroll
  for (int j = 0; j < 8; j++) o[j] = (short)f2bf(v[j]);
  return o;
}
static __device__ inline int swizzle_wg(int b) {
  return ((b & 7) << 6) | (b >> 3);   // 512 blocks, bijective
}

// ---------------------------------------------------------------------------
// K1: fused prep + stageA + stageB, weights converted ON THE FLY from f32
// (weights < 1 MB, L2-resident; conversion is the same RNE as before ->
// bit-identical results, but the convert kernel + wc round-trip is gone).
// 512 blocks x 512 thr (8 waves). Block handles 16 pixels end-to-end.
// ---------------------------------------------------------------------------
__global__ __launch_bounds__(512, 4) void k1_fused(
    const float* __restrict__ low, const float* __restrict__ high,
    const float* __restrict__ w1f, const float* __restrict__ w2f,
    const float* __restrict__ wqf, const float* __restrict__ wofff,
    const float* __restrict__ wkf, const float* __restrict__ wvf,
    const float* __restrict__ b1, const float* __restrict__ b2,
    const float* __restrict__ bq, const float* __restrict__ boff,
    const float* __restrict__ bk, const float* __restrict__ bv,
    short* __restrict__ xh, float* __restrict__ q_t, float* __restrict__ k_t,
    float* __restrict__ off_t, short* __restrict__ v_t) {
  __shared__ short xin_s[16 * 520];
  __shared__ short qf_s[16 * 136];
  __shared__ short vf_s[16 * 136];
  const int tid = threadIdx.x;
  const int wg = swizzle_wg(blockIdx.x);
  const int pix0 = wg * 16;
  const int b = pix0 >> 12;
  const int n0 = pix0 & (NL - 1);

  // ---- phase P: build xin tile (8 channels/thread) ----
  {
    const int nl = tid & 15, cg = tid >> 4;
    const int n = n0 + nl;
    const int y = n >> 6, x = n & 63;
    float sx = x * 0.5f - 0.25f;
    float sy = y * 0.5f - 0.25f;
    float x0f = floorf(sx), y0f = floorf(sy);
    float wx = sx - x0f, wy = sy - y0f;
    int x0i = (int)x0f, y0i = (int)y0f;
    int x0c = min(WH - 1, max(0, x0i)), x1c = min(WH - 1, max(0, x0i + 1));
    int y0c = min(HH - 1, max(0, y0i)), y1c = min(HH - 1, max(0, y0i + 1));
    float w00 = (1.f - wy) * (1.f - wx), w01 = (1.f - wy) * wx;
    float w10 = wy * (1.f - wx),         w11 = wy * wx;
#pragma unroll
    for (int i = 0; i < 8; i++) {
      int c = cg * 8 + i;
      const float* f = high + (size_t)(b * 256 + c) * (HH * WH);
      float v = w00 * f[y0c * WH + x0c] + w01 * f[y0c * WH + x1c]
              + w10 * f[y1c * WH + x0c] + w11 * f[y1c * WH + x1c];
      xin_s[nl * 520 + c] = (short)f2bf(v);
      xin_s[nl * 520 + 256 + c] =
          (short)f2bf(low[(size_t)(b * 256 + c) * NL + n]);
    }
  }
  __syncthreads();

  // ---- store xh (high half of xin, needed by K2 final GEMM) ----
  {
    const int r = tid >> 5, c0 = (tid & 31) * 8;
    s8v v0 = *(const s8v*)(xin_s + r * 520 + c0);
    *(s8v*)(xh + (size_t)(pix0 + r) * 256 + c0) = v0;
  }

  const int wave = tid >> 6, lane = tid & 63;
  const int quad = lane >> 4, id = lane & 15;

  // ---- phase A1: qf = W1 @ xin, M=128 K=512; 1 frag per wave ----
  {
    f32x4 acc = (f32x4){0.f, 0.f, 0.f, 0.f};
    const float* a0 = w1f + (size_t)(wave * 16 + id) * 512 + quad * 8;
    const short* bp = xin_s + id * 520 + quad * 8;
#pragma unroll
    for (int kk = 0; kk < 512; kk += 32)
      acc = __builtin_amdgcn_mfma_f32_16x16x32_bf16(
          cvt8(*(const f32x8*)(a0 + kk)), *(const s8v*)(bp + kk), acc, 0, 0, 0);
    int m0 = wave * 16 + quad * 4;
    s4v o0;
#pragma unroll
    for (int r = 0; r < 4; r++) o0[r] = (short)f2bf(acc[r] + b1[m0 + r]);
    *(s4v*)(qf_s + id * 136 + m0) = o0;
  }

  // ---- phase A2: vf = W2 @ xin[:,0:256], M=128 K=256 ----
  {
    f32x4 acc = (f32x4){0.f, 0.f, 0.f, 0.f};
    const float* a0 = w2f + (size_t)(wave * 16 + id) * 256 + quad * 8;
    const short* bp = xin_s + id * 520 + quad * 8;
#pragma unroll
    for (int kk = 0; kk < 256; kk += 32)
      acc = __builtin_amdgcn_mfma_f32_16x16x32_bf16(
          cvt8(*(const f32x8*)(a0 + kk)), *(const s8v*)(bp + kk), acc, 0, 0, 0);
    int m0 = wave * 16 + quad * 4;
    s4v o0;
#pragma unroll
    for (int r = 0; r < 4; r++) o0[r] = (short)f2bf(acc[r] + b2[m0 + r]);
    *(s4v*)(vf_s + id * 136 + m0) = o0;
  }
  __syncthreads();

  // ---- phase B: 14 m-frags (0:q, 1-4:off, 5:k, 6-13:v), K=128 ----
  for (int f = wave; f < 14; f += 8) {
    const float* ap;
    if      (f == 0) ap = wqf   + (size_t)id * 128;
    else if (f <  5) ap = wofff + (size_t)((f - 1) * 16 + id) * 128;
    else if (f == 5) ap = wkf   + (size_t)id * 128;
    else             ap = wvf   + (size_t)((f - 6) * 16 + id) * 128;
    ap += quad * 8;
    const short* bp = (f < 5 ? qf_s : vf_s) + id * 136 + quad * 8;
    f32x4 acc = (f32x4){0.f, 0.f, 0.f, 0.f};
#pragma unroll
    for (int kk = 0; kk < 128; kk += 32)
      acc = __builtin_amdgcn_mfma_f32_16x16x32_bf16(
          cvt8(*(const f32x8*)(ap + kk)), *(const s8v*)(bp + kk), acc, 0, 0, 0);
    const int pix = pix0 + id;
    const int mq = quad * 4;
    if (f == 0) {
      f32x4 v;
#pragma unroll
      for (int r = 0; r < 4; r++) v[r] = acc[r] + bq[mq + r];
      *(f32x4*)(q_t + (size_t)pix * 16 + mq) = v;
    } else if (f < 5) {
      int m = (f - 1) * 16 + mq;
      f32x4 v;
#pragma unroll
      for (int r = 0; r < 4; r++) v[r] = acc[r] + boff[m + r];
      *(f32x4*)(off_t + (size_t)pix * 64 + m) = v;
    } else if (f == 5) {
      f32x4 v;
#pragma unroll
      for (int r = 0; r < 4; r++) v[r] = acc[r] + bk[mq + r];
      *(f32x4*)(k_t + (size_t)pix * 16 + mq) = v;
    } else {
      int m = (f - 6) * 16 + mq;
      s4v o;
#pragma unroll
      for (int r = 0; r < 4; r++) o[r] = (short)f2bf(acc[r] + bv[m + r]);
      *(s4v*)(v_t + (size_t)pix * 128 + m) = o;
    }
  }
}

// ---------------------------------------------------------------------------
// K2: fused deformable attention + final GEMM (+BN+ReLU).
// 512 blocks x 1024 thr (16 waves). Wave w owns query pix0+w.
// Phase F converts Wb f32->bf16 on the fly (L2-resident, same RNE).
// ---------------------------------------------------------------------------
__global__ __launch_bounds__(1024, 2) void k2_fused(
    const float* __restrict__ q_t, const float* __restrict__ k_t,
    const short* __restrict__ v_t, const float* __restrict__ off_t,
    const short* __restrict__ xh, const float* __restrict__ wbf,
    const float* __restrict__ gamma, const float* __restrict__ beta,
    const float* __restrict__ rmean, const float* __restrict__ rvar,
    float* __restrict__ out) {
  __shared__ float2 s_wi[16][32][4];  // {e*w_tap, idx-as-float-bits}: 16 KB
  __shared__ short attn_s[16 * 136];  // 4.25 KB
  const int tid = threadIdx.x;
  const int wave = tid >> 6, lane = tid & 63;
  const int wg = swizzle_wg(blockIdx.x);
  const int pix0 = wg * 16;

  // ---- phase T: attention, ONE query per wave ----
  {
    const int qidx = pix0 + wave;
    const int b = qidx >> 12;
    const int n = qidx & (NL - 1);
    const int qy = n >> 6, qx = n & 63;

    // offset load first: its result is needed earliest (sample indices)
    const int pt = lane >> 1, h = lane & 1;
    float2 dxy = *(const float2*)(off_t + (size_t)qidx * 64 + 2 * pt);

    const float* qp = q_t + (size_t)qidx * 16;
    float qreg[16];
#pragma unroll
    for (int i = 0; i < 16; i += 4) {
      float4 t4 = *(const float4*)(qp + i);
      qreg[i] = t4.x; qreg[i + 1] = t4.y; qreg[i + 2] = t4.z; qreg[i + 3] = t4.w;
    }

    float sx = (float)qx + dxy.x;
    float sy = (float)qy + dxy.y;
    float x0f = floorf(sx), y0f = floorf(sy);
    float wx = sx - x0f, wy = sy - y0f;
    int x0i = (int)x0f, y0i = (int)y0f;
    int x0 = min(63, max(0, x0i)), x1 = min(63, max(0, x0i + 1));
    int y0 = min(63, max(0, y0i)), y1 = min(63, max(0, y0i + 1));

    int   yr  = h ? y1 : y0;
    float wyr = h ? wy : (1.f - wy);
    int   pa = yr * 64 + x0, pb = yr * 64 + x1;
    float wa = wyr * (1.f - wx), wb_ = wyr * wx;

    const float* kb = k_t + (size_t)b * NL * 16;
    float da = 0.f, db = 0.f;
    {
      const float* ka = kb + (size_t)pa * 16;
      const float* kc = kb + (size_t)pb * 16;
#pragma unroll
      for (int i = 0; i < 16; i += 4) {
        float4 a4 = *(const float4*)(ka + i);
        float4 c4 = *(const float4*)(kc + i);
        da = fmaf(qreg[i], a4.x, da); da = fmaf(qreg[i + 1], a4.y, da);
        da = fmaf(qreg[i + 2], a4.z, da); da = fmaf(qreg[i + 3], a4.w, da);
        db = fmaf(qreg[i], c4.x, db); db = fmaf(qreg[i + 1], c4.y, db);
        db = fmaf(qreg[i + 2], c4.z, db); db = fmaf(qreg[i + 3], c4.w, db);
      }
    }
    float part = wa * da + wb_ * db;
    part += __shfl_xor(part, 1, 64);
    float logit = part * 0.25f;

    // no max-reduce: logits structurally bounded far below exp overflow;
    // the normalization (2/ssum) cancels any common scale exactly.
    float e = __expf(logit);

    // per-wave table with UNNORMALIZED weights; same-wave LDS RAW is
    // lgkmcnt-ordered -> no barrier. idx pre-scaled to short-offset (pix*128).
    s_wi[wave][pt][2 * h + 0] = make_float2(e * wa,  __int_as_float(pa << 7));
    s_wi[wave][pt][2 * h + 1] = make_float2(e * wb_, __int_as_float(pb << 7));

    // ---- V-gather: tap-parallel, 8 channels per lane per point ----
    const int t = lane >> 4, chunk = lane & 15;
    const short* vb = v_t + (size_t)b * NL * 128 + chunk * 8;
    float o[8];
#pragma unroll
    for (int j = 0; j < 8; j++) o[j] = 0.f;
    for (int base = 0; base < 32; base += 8) {
      float w8[8]; int ix[8];
#pragma unroll
      for (int j = 0; j < 8; j++) {
        float2 wi = s_wi[wave][base + j][t];   // one ds_read_b64
        w8[j] = wi.x;
        ix[j] = __float_as_int(wi.y);
      }
      uint4 u[8];
#pragma unroll
      for (int j = 0; j < 8; j++) u[j] = *(const uint4*)(vb + ix[j]);
#pragma unroll
      for (int j = 0; j < 8; j++) {
        o[0] = fmaf(w8[j], bfbits2f(u[j].x & 0xffffu), o[0]);
        o[1] = fmaf(w8[j], bfbits2f(u[j].x >> 16),     o[1]);
        o[2] = fmaf(w8[j], bfbits2f(u[j].y & 0xffffu), o[2]);
        o[3] = fmaf(w8[j], bfbits2f(u[j].y >> 16),     o[3]);
        o[4] = fmaf(w8[j], bfbits2f(u[j].z & 0xffffu), o[4]);
        o[5] = fmaf(w8[j], bfbits2f(u[j].z >> 16),     o[5]);
        o[6] = fmaf(w8[j], bfbits2f(u[j].w & 0xffffu), o[6]);
        o[7] = fmaf(w8[j], bfbits2f(u[j].w >> 16),     o[7]);
      }
    }
    // deferred softmax denominator (overlaps gather tail); each point is
    // double-counted across h -> factor 2.
    float ssum = e;
#pragma unroll
    for (int s = 32; s > 0; s >>= 1) ssum += __shfl_xor(ssum, s, 64);
    float scale = 2.f / ssum;

    // reduce across the 4 tap-groups (lane bits 4,5), then normalize
#pragma unroll
    for (int j = 0; j < 8; j++) {
      o[j] += __shfl_xor(o[j], 16, 64);
      o[j] += __shfl_xor(o[j], 32, 64);
    }
    if (t == 0) {
      uint4 pk;
      pk.x = (unsigned)f2bf(o[0] * scale) | ((unsigned)f2bf(o[1] * scale) << 16);
      pk.y = (unsigned)f2bf(o[2] * scale) | ((unsigned)f2bf(o[3] * scale) << 16);
      pk.z = (unsigned)f2bf(o[4] * scale) | ((unsigned)f2bf(o[5] * scale) << 16);
      pk.w = (unsigned)f2bf(o[6] * scale) | ((unsigned)f2bf(o[7] * scale) << 16);
      *(uint4*)(attn_s + wave * 136 + chunk * 8) = pk;
    }
  }
  __syncthreads();

  // ---- phase F: final GEMM, N=16 px, M=256 over 16 waves (1 frag/wave) ----
  {
    const int quad = lane >> 4, id = lane & 15;
    const int m0 = wave * 16;
    const int pix = pix0 + id;

    f32x4 acc = (f32x4){0.f, 0.f, 0.f, 0.f};
    const float* ap = wbf + (size_t)(m0 + id) * 384 + quad * 8;
    const short* bs = attn_s + id * 136 + quad * 8;
    const short* bg = xh + (size_t)pix * 256 + quad * 8;
#pragma unroll
    for (int k = 0; k < 4; k++)
      acc = __builtin_amdgcn_mfma_f32_16x16x32_bf16(
          cvt8(*(const f32x8*)(ap + k * 32)), *(const s8v*)(bs + k * 32),
          acc, 0, 0, 0);
#pragma unroll
    for (int k = 0; k < 8; k++)
      acc = __builtin_amdgcn_mfma_f32_16x16x32_bf16(
          cvt8(*(const f32x8*)(ap + 128 + k * 32)), *(const s8v*)(bg + k * 32),
          acc, 0, 0, 0);

    const int bb = pix >> 12, nlow = pix & (NL - 1);
    const int mbase = m0 + quad * 4;
#pragma unroll
    for (int r = 0; r < 4; r++) {
      int o = mbase + r;
      float s  = gamma[o] * rsqrtf(rvar[o] + 1e-5f);
      float sh = beta[o] - rmean[o] * s;
      __builtin_nontemporal_store(fmaxf(fmaf(acc[r], s, sh), 0.f),
                                  &out[((size_t)bb * 256 + o) * NL + nlow]);
    }
  }
}

// ---------------------------------------------------------------------------
extern "C" void kernel_launch(void* const* d_in, const int* in_sizes, int n_in,
                              void* d_out, int out_size, void* d_ws, size_t ws_size,
                              hipStream_t stream) {
  const float* low   = (const float*)d_in[0];
  const float* high  = (const float*)d_in[1];
  const float* W1    = (const float*)d_in[2];
  const float* b1    = (const float*)d_in[3];
  const float* W2    = (const float*)d_in[4];
  const float* b2    = (const float*)d_in[5];
  const float* Wq    = (const float*)d_in[6];
  const float* bq    = (const float*)d_in[7];
  const float* Wk    = (const float*)d_in[8];
  const float* bk    = (const float*)d_in[9];
  const float* Wv    = (const float*)d_in[10];
  const float* bv    = (const float*)d_in[11];
  const float* Woff  = (const float*)d_in[12];
  const float* boff  = (const float*)d_in[13];
  const float* Wb    = (const float*)d_in[14];
  const float* gamma = (const float*)d_in[15];
  const float* beta  = (const float*)d_in[16];
  const float* rmean = (const float*)d_in[17];
  const float* rvar  = (const float*)d_in[18];
  float* out = (float*)d_out;

  short* ws    = (short*)d_ws;
  short* xh    = ws;                    // [8192][256] bf16 = 2,097,152 sh
  short* v_t   = xh + 2097152;          // [8192][128] bf16
  float* q_t   = (float*)(v_t + 1048576); // [8192][16] f32
  float* k_t   = q_t + 131072;          // [8192][16] f32
  float* off_t = k_t + 131072;          // [8192][64] f32

  k1_fused<<<512, 512, 0, stream>>>(low, high, W1, W2, Wq, Woff, Wk, Wv,
                                    b1, b2, bq, boff, bk, bv,
                                    xh, q_t, k_t, off_t, v_t);
  k2_fused<<<512, 1024, 0, stream>>>(q_t, k_t, v_t, off_t, xh, Wb,
                                     gamma, beta, rmean, rvar, out);
}

// Round 6
// 153.128 us; speedup vs baseline: 1.1209x; 1.1209x over previous
//
#include <hip/hip_runtime.h>
#include <hip/hip_bf16.h>

#define NL 4096   // 64*64 low-res pixels
#define HH 32
#define WH 32

typedef __attribute__((ext_vector_type(8))) short s8v;   // 8 bf16 MFMA A/B frag
typedef __attribute__((ext_vector_type(4))) short s4v;   // 4 bf16 (8B)
typedef __attribute__((ext_vector_type(4))) float f32x4; // MFMA C/D frag

static __device__ inline unsigned short f2bf(float x) {
  __hip_bfloat16 h = __float2bfloat16(x);   // RNE
  return *reinterpret_cast<unsigned short*>(&h);
}
static __device__ inline float bfbits2f(unsigned int lo16) {
  unsigned int u = lo16 << 16;
  return *reinterpret_cast<float*>(&u);
}
static __device__ inline int swizzle_wg(int b) {
  return ((b & 7) << 6) | (b >> 3);   // 512 blocks, bijective
}

// ---------------------------------------------------------------------------
// Weight fp32 -> bf16, packed (4 elems/thread):
//   [0,65536)        W1   [128][512]
//   [65536,98304)    W2   [128][256]
//   [98304,100352)   Wq   [16][128]   \
//   [100352,108544)  Woff [64][128]    | stage-B concat: 224 rows, K=128
//   [108544,110592)  Wk   [16][128]    |
//   [110592,126976)  Wv   [128][128]  /
//   [126976,225280)  Wb   [256][384]
// ---------------------------------------------------------------------------
__global__ __launch_bounds__(256) void convert_weights_k(
    const float* __restrict__ w1, const float* __restrict__ w2,
    const float* __restrict__ wq, const float* __restrict__ woff,
    const float* __restrict__ wk, const float* __restrict__ wv,
    const float* __restrict__ wb, short* __restrict__ dst) {
  int i = (blockIdx.x * 256 + threadIdx.x) * 4;
  const float* src; int off;
  if      (i <  65536) { src = w1;   off = 0; }
  else if (i <  98304) { src = w2;   off = 65536; }
  else if (i < 100352) { src = wq;   off = 98304; }
  else if (i < 108544) { src = woff; off = 100352; }
  else if (i < 110592) { src = wk;   off = 108544; }
  else if (i < 126976) { src = wv;   off = 110592; }
  else if (i < 225280) { src = wb;   off = 126976; }
  else return;
  float4 v = *(const float4*)(src + (i - off));
  s4v o;
  o[0] = (short)f2bf(v.x); o[1] = (short)f2bf(v.y);
  o[2] = (short)f2bf(v.z); o[3] = (short)f2bf(v.w);
  *(s4v*)(dst + i) = o;
}

// ---------------------------------------------------------------------------
// K1: fused prep + stageA + stageB. 512 blocks x 512 thr (8 waves).
// Block handles 16 pixels end-to-end.  (unchanged round-3 structure)
// ---------------------------------------------------------------------------
__global__ __launch_bounds__(512, 4) void k1_fused(
    const float* __restrict__ low, const float* __restrict__ high,
    const short* __restrict__ wc,
    const float* __restrict__ b1, const float* __restrict__ b2,
    const float* __restrict__ bq, const float* __restrict__ boff,
    const float* __restrict__ bk, const float* __restrict__ bv,
    short* __restrict__ xh, float* __restrict__ q_t, float* __restrict__ k_t,
    float* __restrict__ off_t, short* __restrict__ v_t) {
  __shared__ short xin_s[16 * 520];
  __shared__ short qf_s[16 * 136];
  __shared__ short vf_s[16 * 136];
  const int tid = threadIdx.x;
  const int wg = swizzle_wg(blockIdx.x);
  const int pix0 = wg * 16;
  const int b = pix0 >> 12;
  const int n0 = pix0 & (NL - 1);

  // ---- phase P: build xin tile (8 channels/thread) ----
  {
    const int nl = tid & 15, cg = tid >> 4;
    const int n = n0 + nl;
    const int y = n >> 6, x = n & 63;
    float sx = x * 0.5f - 0.25f;
    float sy = y * 0.5f - 0.25f;
    float x0f = floorf(sx), y0f = floorf(sy);
    float wx = sx - x0f, wy = sy - y0f;
    int x0i = (int)x0f, y0i = (int)y0f;
    int x0c = min(WH - 1, max(0, x0i)), x1c = min(WH - 1, max(0, x0i + 1));
    int y0c = min(HH - 1, max(0, y0i)), y1c = min(HH - 1, max(0, y0i + 1));
    float w00 = (1.f - wy) * (1.f - wx), w01 = (1.f - wy) * wx;
    float w10 = wy * (1.f - wx),         w11 = wy * wx;
#pragma unroll
    for (int i = 0; i < 8; i++) {
      int c = cg * 8 + i;
      const float* f = high + (size_t)(b * 256 + c) * (HH * WH);
      float v = w00 * f[y0c * WH + x0c] + w01 * f[y0c * WH + x1c]
              + w10 * f[y1c * WH + x0c] + w11 * f[y1c * WH + x1c];
      xin_s[nl * 520 + c] = (short)f2bf(v);
      xin_s[nl * 520 + 256 + c] =
          (short)f2bf(low[(size_t)(b * 256 + c) * NL + n]);
    }
  }
  __syncthreads();

  // ---- store xh (high half of xin, needed by K2 final GEMM) ----
  {
    const int r = tid >> 5, c0 = (tid & 31) * 8;
    s8v v0 = *(const s8v*)(xin_s + r * 520 + c0);
    *(s8v*)(xh + (size_t)(pix0 + r) * 256 + c0) = v0;
  }

  const int wave = tid >> 6, lane = tid & 63;
  const int quad = lane >> 4, id = lane & 15;

  // ---- phase A1: qf = W1 @ xin, M=128 K=512; 1 frag per wave ----
  {
    f32x4 acc = (f32x4){0.f, 0.f, 0.f, 0.f};
    const short* a0 = wc + (size_t)(wave * 16 + id) * 512 + quad * 8;
    const short* bp = xin_s + id * 520 + quad * 8;
#pragma unroll
    for (int kk = 0; kk < 512; kk += 32)
      acc = __builtin_amdgcn_mfma_f32_16x16x32_bf16(
          *(const s8v*)(a0 + kk), *(const s8v*)(bp + kk), acc, 0, 0, 0);
    int m0 = wave * 16 + quad * 4;
    s4v o0;
#pragma unroll
    for (int r = 0; r < 4; r++) o0[r] = (short)f2bf(acc[r] + b1[m0 + r]);
    *(s4v*)(qf_s + id * 136 + m0) = o0;
  }

  // ---- phase A2: vf = W2 @ xin[:,0:256], M=128 K=256 ----
  {
    f32x4 acc = (f32x4){0.f, 0.f, 0.f, 0.f};
    const short* a0 = wc + 65536 + (size_t)(wave * 16 + id) * 256 + quad * 8;
    const short* bp = xin_s + id * 520 + quad * 8;
#pragma unroll
    for (int kk = 0; kk < 256; kk += 32)
      acc = __builtin_amdgcn_mfma_f32_16x16x32_bf16(
          *(const s8v*)(a0 + kk), *(const s8v*)(bp + kk), acc, 0, 0, 0);
    int m0 = wave * 16 + quad * 4;
    s4v o0;
#pragma unroll
    for (int r = 0; r < 4; r++) o0[r] = (short)f2bf(acc[r] + b2[m0 + r]);
    *(s4v*)(vf_s + id * 136 + m0) = o0;
  }
  __syncthreads();

  // ---- phase B: 14 m-frags (0:q, 1-4:off, 5:k, 6-13:v), K=128 ----
  for (int f = wave; f < 14; f += 8) {
    const short* ap = wc + 98304 + (size_t)(f * 16 + id) * 128 + quad * 8;
    const short* bp = (f < 5 ? qf_s : vf_s) + id * 136 + quad * 8;
    f32x4 acc = (f32x4){0.f, 0.f, 0.f, 0.f};
#pragma unroll
    for (int kk = 0; kk < 128; kk += 32)
      acc = __builtin_amdgcn_mfma_f32_16x16x32_bf16(
          *(const s8v*)(ap + kk), *(const s8v*)(bp + kk), acc, 0, 0, 0);
    const int pix = pix0 + id;
    const int mq = quad * 4;
    if (f == 0) {
      f32x4 v;
#pragma unroll
      for (int r = 0; r < 4; r++) v[r] = acc[r] + bq[mq + r];
      *(f32x4*)(q_t + (size_t)pix * 16 + mq) = v;
    } else if (f < 5) {
      int m = (f - 1) * 16 + mq;
      f32x4 v;
#pragma unroll
      for (int r = 0; r < 4; r++) v[r] = acc[r] + boff[m + r];
      *(f32x4*)(off_t + (size_t)pix * 64 + m) = v;
    } else if (f == 5) {
      f32x4 v;
#pragma unroll
      for (int r = 0; r < 4; r++) v[r] = acc[r] + bk[mq + r];
      *(f32x4*)(k_t + (size_t)pix * 16 + mq) = v;
    } else {
      int m = (f - 6) * 16 + mq;
      s4v o;
#pragma unroll
      for (int r = 0; r < 4; r++) o[r] = (short)f2bf(acc[r] + bv[m + r]);
      *(s4v*)(v_t + (size_t)pix * 128 + m) = o;
    }
  }
}

// ---------------------------------------------------------------------------
// K2: fused deformable attention + final GEMM (+BN+ReLU).
// CHANGED: 512 blocks x 512 thr (8 waves), 2 queries/wave, lb(512,8):
// VGPR<=64 -> 4 blocks/CU = 32 waves/CU (vs ~18 before) to hide the L2
// gather latency that dominates (round-5 PMC: 80% stall, VALU 19%, MFMA 1%).
// Barrier scope halves (8 waves) before phase F.
// ---------------------------------------------------------------------------
__global__ __launch_bounds__(512, 8) void k2_fused(
    const float* __restrict__ q_t, const float* __restrict__ k_t,
    const short* __restrict__ v_t, const float* __restrict__ off_t,
    const short* __restrict__ xh, const short* __restrict__ wb,
    const float* __restrict__ gamma, const float* __restrict__ beta,
    const float* __restrict__ rmean, const float* __restrict__ rvar,
    float* __restrict__ out) {
  __shared__ float2 s_wi[16][32][4];  // {e*w_tap, idx-as-float-bits}: 16 KB
  __shared__ short attn_s[16 * 136];  // 4.25 KB
  const int tid = threadIdx.x;
  const int wave = tid >> 6, lane = tid & 63;
  const int wg = swizzle_wg(blockIdx.x);
  const int pix0 = wg * 16;

  // ---- phase T: attention, TWO queries per wave (sequential) ----
  for (int qi = 0; qi < 2; qi++) {
    const int ql = wave * 2 + qi;
    const int qidx = pix0 + ql;
    const int b = qidx >> 12;
    const int n = qidx & (NL - 1);
    const int qy = n >> 6, qx = n & 63;

    // offset load first: its result is needed earliest (sample indices)
    const int pt = lane >> 1, h = lane & 1;
    float2 dxy = *(const float2*)(off_t + (size_t)qidx * 64 + 2 * pt);

    const float* qp = q_t + (size_t)qidx * 16;
    float qreg[16];
#pragma unroll
    for (int i = 0; i < 16; i += 4) {
      float4 t4 = *(const float4*)(qp + i);
      qreg[i] = t4.x; qreg[i + 1] = t4.y; qreg[i + 2] = t4.z; qreg[i + 3] = t4.w;
    }

    float sx = (float)qx + dxy.x;
    float sy = (float)qy + dxy.y;
    float x0f = floorf(sx), y0f = floorf(sy);
    float wx = sx - x0f, wy = sy - y0f;
    int x0i = (int)x0f, y0i = (int)y0f;
    int x0 = min(63, max(0, x0i)), x1 = min(63, max(0, x0i + 1));
    int y0 = min(63, max(0, y0i)), y1 = min(63, max(0, y0i + 1));

    int   yr  = h ? y1 : y0;
    float wyr = h ? wy : (1.f - wy);
    int   pa = yr * 64 + x0, pb = yr * 64 + x1;
    float wa = wyr * (1.f - wx), wb_ = wyr * wx;

    const float* kb = k_t + (size_t)b * NL * 16;
    float da = 0.f, db = 0.f;
    {
      const float* ka = kb + (size_t)pa * 16;
      const float* kc = kb + (size_t)pb * 16;
#pragma unroll
      for (int i = 0; i < 16; i += 4) {
        float4 a4 = *(const float4*)(ka + i);
        float4 c4 = *(const float4*)(kc + i);
        da = fmaf(qreg[i], a4.x, da); da = fmaf(qreg[i + 1], a4.y, da);
        da = fmaf(qreg[i + 2], a4.z, da); da = fmaf(qreg[i + 3], a4.w, da);
        db = fmaf(qreg[i], c4.x, db); db = fmaf(qreg[i + 1], c4.y, db);
        db = fmaf(qreg[i + 2], c4.z, db); db = fmaf(qreg[i + 3], c4.w, db);
      }
    }
    float part = wa * da + wb_ * db;
    part += __shfl_xor(part, 1, 64);
    float logit = part * 0.25f;

    // no max-reduce: logits structurally bounded far below exp overflow;
    // the normalization (2/ssum) cancels any common scale exactly.
    float e = __expf(logit);

    // per-wave table with UNNORMALIZED weights; same-wave LDS RAW is
    // lgkmcnt-ordered -> no barrier. idx pre-scaled to short-offset (pix*128).
    s_wi[ql][pt][2 * h + 0] = make_float2(e * wa,  __int_as_float(pa << 7));
    s_wi[ql][pt][2 * h + 1] = make_float2(e * wb_, __int_as_float(pb << 7));

    // ---- V-gather: tap-parallel, 8 channels per lane per point ----
    const int t = lane >> 4, chunk = lane & 15;
    const short* vb = v_t + (size_t)b * NL * 128 + chunk * 8;
    float o[8];
#pragma unroll
    for (int j = 0; j < 8; j++) o[j] = 0.f;
    for (int base = 0; base < 32; base += 8) {
      float w8[8]; int ix[8];
#pragma unroll
      for (int j = 0; j < 8; j++) {
        float2 wi = s_wi[ql][base + j][t];   // one ds_read_b64
        w8[j] = wi.x;
        ix[j] = __float_as_int(wi.y);
      }
      uint4 u[8];
#pragma unroll
      for (int j = 0; j < 8; j++) u[j] = *(const uint4*)(vb + ix[j]);
#pragma unroll
      for (int j = 0; j < 8; j++) {
        o[0] = fmaf(w8[j], bfbits2f(u[j].x & 0xffffu), o[0]);
        o[1] = fmaf(w8[j], bfbits2f(u[j].x >> 16),     o[1]);
        o[2] = fmaf(w8[j], bfbits2f(u[j].y & 0xffffu), o[2]);
        o[3] = fmaf(w8[j], bfbits2f(u[j].y >> 16),     o[3]);
        o[4] = fmaf(w8[j], bfbits2f(u[j].z & 0xffffu), o[4]);
        o[5] = fmaf(w8[j], bfbits2f(u[j].z >> 16),     o[5]);
        o[6] = fmaf(w8[j], bfbits2f(u[j].w & 0xffffu), o[6]);
        o[7] = fmaf(w8[j], bfbits2f(u[j].w >> 16),     o[7]);
      }
    }
    // deferred softmax denominator (overlaps gather tail); each point is
    // double-counted across h -> factor 2.
    float ssum = e;
#pragma unroll
    for (int s = 32; s > 0; s >>= 1) ssum += __shfl_xor(ssum, s, 64);
    float scale = 2.f / ssum;

    // reduce across the 4 tap-groups (lane bits 4,5), then normalize
#pragma unroll
    for (int j = 0; j < 8; j++) {
      o[j] += __shfl_xor(o[j], 16, 64);
      o[j] += __shfl_xor(o[j], 32, 64);
    }
    if (t == 0) {
      uint4 pk;
      pk.x = (unsigned)f2bf(o[0] * scale) | ((unsigned)f2bf(o[1] * scale) << 16);
      pk.y = (unsigned)f2bf(o[2] * scale) | ((unsigned)f2bf(o[3] * scale) << 16);
      pk.z = (unsigned)f2bf(o[4] * scale) | ((unsigned)f2bf(o[5] * scale) << 16);
      pk.w = (unsigned)f2bf(o[6] * scale) | ((unsigned)f2bf(o[7] * scale) << 16);
      *(uint4*)(attn_s + ql * 136 + chunk * 8) = pk;
    }
  }
  __syncthreads();

  // ---- phase F: final GEMM, N=16 px, M=256 over 8 waves x 2 frags ----
  {
    const int quad = lane >> 4, id = lane & 15;
    const int pix = pix0 + id;
    const short* bs = attn_s + id * 136 + quad * 8;
    const short* bg = xh + (size_t)pix * 256 + quad * 8;
    const int bb = pix >> 12, nlow = pix & (NL - 1);
#pragma unroll
    for (int j = 0; j < 2; j++) {
      const int m0 = wave * 16 + j * 128;
      f32x4 acc = (f32x4){0.f, 0.f, 0.f, 0.f};
      const short* ap = wb + (size_t)(m0 + id) * 384 + quad * 8;
#pragma unroll
      for (int k = 0; k < 4; k++)
        acc = __builtin_amdgcn_mfma_f32_16x16x32_bf16(
            *(const s8v*)(ap + k * 32), *(const s8v*)(bs + k * 32), acc, 0, 0, 0);
#pragma unroll
      for (int k = 0; k < 8; k++)
        acc = __builtin_amdgcn_mfma_f32_16x16x32_bf16(
            *(const s8v*)(ap + 128 + k * 32), *(const s8v*)(bg + k * 32), acc, 0, 0, 0);

      const int mbase = m0 + quad * 4;
#pragma unroll
      for (int r = 0; r < 4; r++) {
        int o = mbase + r;
        float s  = gamma[o] * rsqrtf(rvar[o] + 1e-5f);
        float sh = beta[o] - rmean[o] * s;
        __builtin_nontemporal_store(fmaxf(fmaf(acc[r], s, sh), 0.f),
                                    &out[((size_t)bb * 256 + o) * NL + nlow]);
      }
    }
  }
}

// ---------------------------------------------------------------------------
extern "C" void kernel_launch(void* const* d_in, const int* in_sizes, int n_in,
                              void* d_out, int out_size, void* d_ws, size_t ws_size,
                              hipStream_t stream) {
  const float* low   = (const float*)d_in[0];
  const float* high  = (const float*)d_in[1];
  const float* W1    = (const float*)d_in[2];
  const float* b1    = (const float*)d_in[3];
  const float* W2    = (const float*)d_in[4];
  const float* b2    = (const float*)d_in[5];
  const float* Wq    = (const float*)d_in[6];
  const float* bq    = (const float*)d_in[7];
  const float* Wk    = (const float*)d_in[8];
  const float* bk    = (const float*)d_in[9];
  const float* Wv    = (const float*)d_in[10];
  const float* bv    = (const float*)d_in[11];
  const float* Woff  = (const float*)d_in[12];
  const float* boff  = (const float*)d_in[13];
  const float* Wb    = (const float*)d_in[14];
  const float* gamma = (const float*)d_in[15];
  const float* beta  = (const float*)d_in[16];
  const float* rmean = (const float*)d_in[17];
  const float* rvar  = (const float*)d_in[18];
  float* out = (float*)d_out;

  short* ws    = (short*)d_ws;
  short* xh    = ws;                    // [8192][256] bf16 = 2,097,152 sh
  short* v_t   = xh + 2097152;          // [8192][128] bf16
  short* wc    = v_t + 1048576;         // 225,280 bf16
  float* q_t   = (float*)(wc + 225280); // [8192][16] f32
  float* k_t   = q_t + 131072;          // [8192][16] f32
  float* off_t = k_t + 131072;          // [8192][64] f32

  convert_weights_k<<<880, 256, 0, stream>>>(W1, W2, Wq, Woff, Wk, Wv, Wb, wc);
  k1_fused<<<512, 512, 0, stream>>>(low, high, wc, b1, b2, bq, boff, bk, bv,
                                    xh, q_t, k_t, off_t, v_t);
  k2_fused<<<512, 512, 0, stream>>>(q_t, k_t, v_t, off_t, xh, wc + 126976,
                                    gamma, beta, rmean, rvar, out);
}

// Round 7
// 152.511 us; speedup vs baseline: 1.1255x; 1.0040x over previous
//
#include <hip/hip_runtime.h>
#include <hip/hip_bf16.h>

#define NL 4096   // 64*64 low-res pixels
#define HH 32
#define WH 32

typedef __attribute__((ext_vector_type(8))) short s8v;   // 8 bf16 MFMA A/B frag
typedef __attribute__((ext_vector_type(4))) short s4v;   // 4 bf16 (8B)
typedef __attribute__((ext_vector_type(4))) float f32x4; // MFMA C/D frag

static __device__ inline unsigned short f2bf(float x) {
  __hip_bfloat16 h = __float2bfloat16(x);   // RNE
  return *reinterpret_cast<unsigned short*>(&h);
}
static __device__ inline float bfbits2f(unsigned int lo16) {
  unsigned int u = lo16 << 16;
  return *reinterpret_cast<float*>(&u);
}
static __device__ inline int swizzle_wg(int b) {
  return ((b & 7) << 6) | (b >> 3);   // 512 blocks, bijective
}

// ---------------------------------------------------------------------------
// Weight fp32 -> bf16, packed (4 elems/thread):
//   [0,65536) W1 | [65536,98304) W2 | [98304,100352) Wq | [100352,108544) Woff
//   [108544,110592) Wk | [110592,126976) Wv | [126976,225280) Wb
// ---------------------------------------------------------------------------
__global__ __launch_bounds__(256) void convert_weights_k(
    const float* __restrict__ w1, const float* __restrict__ w2,
    const float* __restrict__ wq, const float* __restrict__ woff,
    const float* __restrict__ wk, const float* __restrict__ wv,
    const float* __restrict__ wb, short* __restrict__ dst) {
  int i = (blockIdx.x * 256 + threadIdx.x) * 4;
  const float* src; int off;
  if      (i <  65536) { src = w1;   off = 0; }
  else if (i <  98304) { src = w2;   off = 65536; }
  else if (i < 100352) { src = wq;   off = 98304; }
  else if (i < 108544) { src = woff; off = 100352; }
  else if (i < 110592) { src = wk;   off = 108544; }
  else if (i < 126976) { src = wv;   off = 110592; }
  else if (i < 225280) { src = wb;   off = 126976; }
  else return;
  float4 v = *(const float4*)(src + (i - off));
  s4v o;
  o[0] = (short)f2bf(v.x); o[1] = (short)f2bf(v.y);
  o[2] = (short)f2bf(v.z); o[3] = (short)f2bf(v.w);
  *(s4v*)(dst + i) = o;
}

// ---------------------------------------------------------------------------
// K1: fused prep + stageA + stageB. 512 blocks x 512 thr (8 waves).
// CHANGED phase P: high rows staged in LDS (2 rows x 10 cols per channel),
// cutting scattered 4B loads 8.4M -> 2.6M device-wide (VMEM-issue floor).
// Low/channel loads issued early into regs to hide under staging.
// ---------------------------------------------------------------------------
__global__ __launch_bounds__(512, 4) void k1_fused(
    const float* __restrict__ low, const float* __restrict__ high,
    const short* __restrict__ wc,
    const float* __restrict__ b1, const float* __restrict__ b2,
    const float* __restrict__ bq, const float* __restrict__ boff,
    const float* __restrict__ bk, const float* __restrict__ bv,
    short* __restrict__ xh, float* __restrict__ q_t, float* __restrict__ k_t,
    float* __restrict__ off_t, short* __restrict__ v_t) {
  __shared__ short xin_s[16 * 520];
  __shared__ short qf_s[16 * 136];
  __shared__ short vf_s[16 * 136];
  __shared__ float hrow_s[256][2][11];   // 10 cols + pad (bank spread)
  const int tid = threadIdx.x;
  const int wg = swizzle_wg(blockIdx.x);
  const int pix0 = wg * 16;
  const int b = pix0 >> 12;
  const int n0 = pix0 & (NL - 1);

  // Block geometry: 16 consecutive pixels in ONE output row.
  const int yrow = n0 >> 6;            // output row (fixed)
  const int x0blk = n0 & 63;           // 0/16/32/48
  const int xc0 = (x0blk >> 1) - 1;    // unclamped base input col (-1/7/15/23)

  // vertical taps (uniform over the block)
  float syf = yrow * 0.5f - 0.25f;
  float y0f = floorf(syf);
  float wy = syf - y0f;
  int y0i = (int)y0f;
  int y0c = min(HH - 1, max(0, y0i)), y1c = min(HH - 1, max(0, y0i + 1));

  // ---- issue low loads early (hide under hrow staging) ----
  const int nl = tid & 15, cg = tid >> 4;   // pixel, channel-group
  const int n = n0 + nl;
  float lo_reg[8];
#pragma unroll
  for (int i = 0; i < 8; i++)
    lo_reg[i] = low[(size_t)(b * 256 + cg * 8 + i) * NL + n];

  // ---- stage high rows: thread t -> channel t>>1, row t&1, 10 cols ----
  {
    const int c = tid >> 1, r = tid & 1;
    const int yr = r ? y1c : y0c;
    const float* src = high + ((size_t)(b * 256 + c) * HH + yr) * WH;
#pragma unroll
    for (int j = 0; j < 10; j++) {
      int col = min(WH - 1, max(0, xc0 + j));
      hrow_s[c][r][j] = src[col];
    }
  }
  __syncthreads();

  // ---- phase P: bilinear from LDS + low from regs -> xin tile ----
  {
    const int x = x0blk + nl;
    float sxf = x * 0.5f - 0.25f;
    float x0f_ = floorf(sxf);
    float wx = sxf - x0f_;
    int x0i = (int)x0f_;
    int j0 = min(WH - 1, max(0, x0i)) - xc0;
    int j1 = min(WH - 1, max(0, x0i + 1)) - xc0;
    float w1x = 1.f - wx;
#pragma unroll
    for (int i = 0; i < 8; i++) {
      int c = cg * 8 + i;
      float top = hrow_s[c][0][j0] * w1x + hrow_s[c][0][j1] * wx;
      float bot = hrow_s[c][1][j0] * w1x + hrow_s[c][1][j1] * wx;
      float v = top * (1.f - wy) + bot * wy;
      xin_s[nl * 520 + c] = (short)f2bf(v);
      xin_s[nl * 520 + 256 + c] = (short)f2bf(lo_reg[i]);
    }
  }
  __syncthreads();

  // ---- store xh (high half of xin, needed by K2 final GEMM) ----
  {
    const int r = tid >> 5, c0 = (tid & 31) * 8;
    s8v v0 = *(const s8v*)(xin_s + r * 520 + c0);
    *(s8v*)(xh + (size_t)(pix0 + r) * 256 + c0) = v0;
  }

  const int wave = tid >> 6, lane = tid & 63;
  const int quad = lane >> 4, id = lane & 15;

  // ---- phase A1: qf = W1 @ xin, M=128 K=512; 1 frag per wave ----
  {
    f32x4 acc = (f32x4){0.f, 0.f, 0.f, 0.f};
    const short* a0 = wc + (size_t)(wave * 16 + id) * 512 + quad * 8;
    const short* bp = xin_s + id * 520 + quad * 8;
#pragma unroll
    for (int kk = 0; kk < 512; kk += 32)
      acc = __builtin_amdgcn_mfma_f32_16x16x32_bf16(
          *(const s8v*)(a0 + kk), *(const s8v*)(bp + kk), acc, 0, 0, 0);
    int m0 = wave * 16 + quad * 4;
    s4v o0;
#pragma unroll
    for (int r = 0; r < 4; r++) o0[r] = (short)f2bf(acc[r] + b1[m0 + r]);
    *(s4v*)(qf_s + id * 136 + m0) = o0;
  }

  // ---- phase A2: vf = W2 @ xin[:,0:256], M=128 K=256 ----
  {
    f32x4 acc = (f32x4){0.f, 0.f, 0.f, 0.f};
    const short* a0 = wc + 65536 + (size_t)(wave * 16 + id) * 256 + quad * 8;
    const short* bp = xin_s + id * 520 + quad * 8;
#pragma unroll
    for (int kk = 0; kk < 256; kk += 32)
      acc = __builtin_amdgcn_mfma_f32_16x16x32_bf16(
          *(const s8v*)(a0 + kk), *(const s8v*)(bp + kk), acc, 0, 0, 0);
    int m0 = wave * 16 + quad * 4;
    s4v o0;
#pragma unroll
    for (int r = 0; r < 4; r++) o0[r] = (short)f2bf(acc[r] + b2[m0 + r]);
    *(s4v*)(vf_s + id * 136 + m0) = o0;
  }
  __syncthreads();

  // ---- phase B: 14 m-frags (0:q, 1-4:off, 5:k, 6-13:v), K=128 ----
  for (int f = wave; f < 14; f += 8) {
    const short* ap = wc + 98304 + (size_t)(f * 16 + id) * 128 + quad * 8;
    const short* bp = (f < 5 ? qf_s : vf_s) + id * 136 + quad * 8;
    f32x4 acc = (f32x4){0.f, 0.f, 0.f, 0.f};
#pragma unroll
    for (int kk = 0; kk < 128; kk += 32)
      acc = __builtin_amdgcn_mfma_f32_16x16x32_bf16(
          *(const s8v*)(ap + kk), *(const s8v*)(bp + kk), acc, 0, 0, 0);
    const int pix = pix0 + id;
    const int mq = quad * 4;
    if (f == 0) {
      f32x4 v;
#pragma unroll
      for (int r = 0; r < 4; r++) v[r] = acc[r] + bq[mq + r];
      *(f32x4*)(q_t + (size_t)pix * 16 + mq) = v;
    } else if (f < 5) {
      int m = (f - 1) * 16 + mq;
      f32x4 v;
#pragma unroll
      for (int r = 0; r < 4; r++) v[r] = acc[r] + boff[m + r];
      *(f32x4*)(off_t + (size_t)pix * 64 + m) = v;
    } else if (f == 5) {
      f32x4 v;
#pragma unroll
      for (int r = 0; r < 4; r++) v[r] = acc[r] + bk[mq + r];
      *(f32x4*)(k_t + (size_t)pix * 16 + mq) = v;
    } else {
      int m = (f - 6) * 16 + mq;
      s4v o;
#pragma unroll
      for (int r = 0; r < 4; r++) o[r] = (short)f2bf(acc[r] + bv[m + r]);
      *(s4v*)(v_t + (size_t)pix * 128 + m) = o;
    }
  }
}

// ---------------------------------------------------------------------------
// K2: fused deformable attention + final GEMM (+BN+ReLU).
// 512 blocks x 512 thr (8 waves), 2 queries/wave, lb(512,8).
// CHANGED: xh tile staged in LDS (load issued at kernel start, written just
// before the barrier -> HBM latency hidden under attention; removes the 8x
// redundant per-wave xh re-reads in phase F).
// ---------------------------------------------------------------------------
__global__ __launch_bounds__(512, 8) void k2_fused(
    const float* __restrict__ q_t, const float* __restrict__ k_t,
    const short* __restrict__ v_t, const float* __restrict__ off_t,
    const short* __restrict__ xh, const short* __restrict__ wb,
    const float* __restrict__ gamma, const float* __restrict__ beta,
    const float* __restrict__ rmean, const float* __restrict__ rvar,
    float* __restrict__ out) {
  __shared__ float2 s_wi[16][32][4];  // {e*w_tap, idx-as-float-bits}: 16 KB
  __shared__ short attn_s[16 * 136];  // 4.25 KB
  __shared__ short xh_s[16][264];     // 8.25 KB (pad 264: 2-way max, free)
  const int tid = threadIdx.x;
  const int wave = tid >> 6, lane = tid & 63;
  const int wg = swizzle_wg(blockIdx.x);
  const int pix0 = wg * 16;

  // ---- issue xh tile load NOW; consumed after attention (T14 split) ----
  const int sp = tid >> 5, sc = (tid & 31) * 8;
  uint4 xh_reg = *(const uint4*)(xh + (size_t)(pix0 + sp) * 256 + sc);

  // ---- phase T: attention, TWO queries per wave (sequential) ----
  for (int qi = 0; qi < 2; qi++) {
    const int ql = wave * 2 + qi;
    const int qidx = pix0 + ql;
    const int b = qidx >> 12;
    const int n = qidx & (NL - 1);
    const int qy = n >> 6, qx = n & 63;

    const int pt = lane >> 1, h = lane & 1;
    float2 dxy = *(const float2*)(off_t + (size_t)qidx * 64 + 2 * pt);

    const float* qp = q_t + (size_t)qidx * 16;
    float qreg[16];
#pragma unroll
    for (int i = 0; i < 16; i += 4) {
      float4 t4 = *(const float4*)(qp + i);
      qreg[i] = t4.x; qreg[i + 1] = t4.y; qreg[i + 2] = t4.z; qreg[i + 3] = t4.w;
    }

    float sx = (float)qx + dxy.x;
    float sy = (float)qy + dxy.y;
    float x0f = floorf(sx), y0f = floorf(sy);
    float wx = sx - x0f, wy = sy - y0f;
    int x0i = (int)x0f, y0i = (int)y0f;
    int x0 = min(63, max(0, x0i)), x1 = min(63, max(0, x0i + 1));
    int y0 = min(63, max(0, y0i)), y1 = min(63, max(0, y0i + 1));

    int   yr  = h ? y1 : y0;
    float wyr = h ? wy : (1.f - wy);
    int   pa = yr * 64 + x0, pb = yr * 64 + x1;
    float wa = wyr * (1.f - wx), wb_ = wyr * wx;

    const float* kb = k_t + (size_t)b * NL * 16;
    float da = 0.f, db = 0.f;
    {
      const float* ka = kb + (size_t)pa * 16;
      const float* kc = kb + (size_t)pb * 16;
#pragma unroll
      for (int i = 0; i < 16; i += 4) {
        float4 a4 = *(const float4*)(ka + i);
        float4 c4 = *(const float4*)(kc + i);
        da = fmaf(qreg[i], a4.x, da); da = fmaf(qreg[i + 1], a4.y, da);
        da = fmaf(qreg[i + 2], a4.z, da); da = fmaf(qreg[i + 3], a4.w, da);
        db = fmaf(qreg[i], c4.x, db); db = fmaf(qreg[i + 1], c4.y, db);
        db = fmaf(qreg[i + 2], c4.z, db); db = fmaf(qreg[i + 3], c4.w, db);
      }
    }
    float part = wa * da + wb_ * db;
    part += __shfl_xor(part, 1, 64);
    float logit = part * 0.25f;

    // no max-reduce: logits structurally bounded; 2/ssum cancels scale.
    float e = __expf(logit);

    s_wi[ql][pt][2 * h + 0] = make_float2(e * wa,  __int_as_float(pa << 7));
    s_wi[ql][pt][2 * h + 1] = make_float2(e * wb_, __int_as_float(pb << 7));

    // ---- V-gather: tap-parallel, 8 channels per lane per point ----
    const int t = lane >> 4, chunk = lane & 15;
    const short* vb = v_t + (size_t)b * NL * 128 + chunk * 8;
    float o[8];
#pragma unroll
    for (int j = 0; j < 8; j++) o[j] = 0.f;
    for (int base = 0; base < 32; base += 8) {
      float w8[8]; int ix[8];
#pragma unroll
      for (int j = 0; j < 8; j++) {
        float2 wi = s_wi[ql][base + j][t];
        w8[j] = wi.x;
        ix[j] = __float_as_int(wi.y);
      }
      uint4 u[8];
#pragma unroll
      for (int j = 0; j < 8; j++) u[j] = *(const uint4*)(vb + ix[j]);
#pragma unroll
      for (int j = 0; j < 8; j++) {
        o[0] = fmaf(w8[j], bfbits2f(u[j].x & 0xffffu), o[0]);
        o[1] = fmaf(w8[j], bfbits2f(u[j].x >> 16),     o[1]);
        o[2] = fmaf(w8[j], bfbits2f(u[j].y & 0xffffu), o[2]);
        o[3] = fmaf(w8[j], bfbits2f(u[j].y >> 16),     o[3]);
        o[4] = fmaf(w8[j], bfbits2f(u[j].z & 0xffffu), o[4]);
        o[5] = fmaf(w8[j], bfbits2f(u[j].z >> 16),     o[5]);
        o[6] = fmaf(w8[j], bfbits2f(u[j].w & 0xffffu), o[6]);
        o[7] = fmaf(w8[j], bfbits2f(u[j].w >> 16),     o[7]);
      }
    }
    float ssum = e;
#pragma unroll
    for (int s = 32; s > 0; s >>= 1) ssum += __shfl_xor(ssum, s, 64);
    float scale = 2.f / ssum;

#pragma unroll
    for (int j = 0; j < 8; j++) {
      o[j] += __shfl_xor(o[j], 16, 64);
      o[j] += __shfl_xor(o[j], 32, 64);
    }
    if (t == 0) {
      uint4 pk;
      pk.x = (unsigned)f2bf(o[0] * scale) | ((unsigned)f2bf(o[1] * scale) << 16);
      pk.y = (unsigned)f2bf(o[2] * scale) | ((unsigned)f2bf(o[3] * scale) << 16);
      pk.z = (unsigned)f2bf(o[4] * scale) | ((unsigned)f2bf(o[5] * scale) << 16);
      pk.w = (unsigned)f2bf(o[6] * scale) | ((unsigned)f2bf(o[7] * scale) << 16);
      *(uint4*)(attn_s + ql * 136 + chunk * 8) = pk;
    }
  }
  // write the prefetched xh tile; barrier orders it for phase F
  *(uint4*)(&xh_s[sp][sc]) = xh_reg;
  __syncthreads();

  // ---- phase F: final GEMM, N=16 px, M=256 over 8 waves x 2 frags ----
  {
    const int quad = lane >> 4, id = lane & 15;
    const int pix = pix0 + id;
    const short* bs = attn_s + id * 136 + quad * 8;
    const short* bg = &xh_s[id][quad * 8];
    const int bb = pix >> 12, nlow = pix & (NL - 1);
#pragma unroll
    for (int j = 0; j < 2; j++) {
      const int m0 = wave * 16 + j * 128;
      f32x4 acc = (f32x4){0.f, 0.f, 0.f, 0.f};
      const short* ap = wb + (size_t)(m0 + id) * 384 + quad * 8;
#pragma unroll
      for (int k = 0; k < 4; k++)
        acc = __builtin_amdgcn_mfma_f32_16x16x32_bf16(
            *(const s8v*)(ap + k * 32), *(const s8v*)(bs + k * 32), acc, 0, 0, 0);
#pragma unroll
      for (int k = 0; k < 8; k++)
        acc = __builtin_amdgcn_mfma_f32_16x16x32_bf16(
            *(const s8v*)(ap + 128 + k * 32), *(const s8v*)(bg + k * 32), acc, 0, 0, 0);

      const int mbase = m0 + quad * 4;
#pragma unroll
      for (int r = 0; r < 4; r++) {
        int o = mbase + r;
        float s  = gamma[o] * rsqrtf(rvar[o] + 1e-5f);
        float sh = beta[o] - rmean[o] * s;
        __builtin_nontemporal_store(fmaxf(fmaf(acc[r], s, sh), 0.f),
                                    &out[((size_t)bb * 256 + o) * NL + nlow]);
      }
    }
  }
}

// ---------------------------------------------------------------------------
extern "C" void kernel_launch(void* const* d_in, const int* in_sizes, int n_in,
                              void* d_out, int out_size, void* d_ws, size_t ws_size,
                              hipStream_t stream) {
  const float* low   = (const float*)d_in[0];
  const float* high  = (const float*)d_in[1];
  const float* W1    = (const float*)d_in[2];
  const float* b1    = (const float*)d_in[3];
  const float* W2    = (const float*)d_in[4];
  const float* b2    = (const float*)d_in[5];
  const float* Wq    = (const float*)d_in[6];
  const float* bq    = (const float*)d_in[7];
  const float* Wk    = (const float*)d_in[8];
  const float* bk    = (const float*)d_in[9];
  const float* Wv    = (const float*)d_in[10];
  const float* bv    = (const float*)d_in[11];
  const float* Woff  = (const float*)d_in[12];
  const float* boff  = (const float*)d_in[13];
  const float* Wb    = (const float*)d_in[14];
  const float* gamma = (const float*)d_in[15];
  const float* beta  = (const float*)d_in[16];
  const float* rmean = (const float*)d_in[17];
  const float* rvar  = (const float*)d_in[18];
  float* out = (float*)d_out;

  short* ws    = (short*)d_ws;
  short* xh    = ws;                    // [8192][256] bf16 = 2,097,152 sh
  short* v_t   = xh + 2097152;          // [8192][128] bf16
  short* wc    = v_t + 1048576;         // 225,280 bf16
  float* q_t   = (float*)(wc + 225280); // [8192][16] f32
  float* k_t   = q_t + 131072;          // [8192][16] f32
  float* off_t = k_t + 131072;          // [8192][64] f32

  convert_weights_k<<<880, 256, 0, stream>>>(W1, W2, Wq, Woff, Wk, Wv, Wb, wc);
  k1_fused<<<512, 512, 0, stream>>>(low, high, wc, b1, b2, bq, boff, bk, bv,
                                    xh, q_t, k_t, off_t, v_t);
  k2_fused<<<512, 512, 0, stream>>>(q_t, k_t, v_t, off_t, xh, wc + 126976,
                                    gamma, beta, rmean, rvar, out);
}

// Round 8
// 137.010 us; speedup vs baseline: 1.2528x; 1.1131x over previous
//
#include <hip/hip_runtime.h>
#include <hip/hip_bf16.h>

#define NL 4096   // 64*64 low-res pixels
#define HH 32
#define WH 32

typedef __attribute__((ext_vector_type(8))) short s8v;   // 8 bf16 MFMA A/B frag
typedef __attribute__((ext_vector_type(4))) short s4v;   // 4 bf16 (8B)
typedef __attribute__((ext_vector_type(4))) float f32x4; // MFMA C/D frag

static __device__ inline unsigned short f2bf(float x) {
  __hip_bfloat16 h = __float2bfloat16(x);   // RNE
  return *reinterpret_cast<unsigned short*>(&h);
}
static __device__ inline float bfbits2f(unsigned int lo16) {
  unsigned int u = lo16 << 16;
  return *reinterpret_cast<float*>(&u);
}
// 256 blocks, 8 XCDs: bijective, contiguous 32-block band per XCD
static __device__ inline int swizzle_wg32(int b) {
  return ((b & 7) << 5) | (b >> 3);
}

// ---------------------------------------------------------------------------
// Weight fp32 -> bf16, packed (4 elems/thread):
//   [0,65536) W1 | [65536,98304) W2 | [98304,100352) Wq | [100352,108544) Woff
//   [108544,110592) Wk | [110592,126976) Wv | [126976,225280) Wb
// ---------------------------------------------------------------------------
__global__ __launch_bounds__(256) void convert_weights_k(
    const float* __restrict__ w1, const float* __restrict__ w2,
    const float* __restrict__ wq, const float* __restrict__ woff,
    const float* __restrict__ wk, const float* __restrict__ wv,
    const float* __restrict__ wb, short* __restrict__ dst) {
  int i = (blockIdx.x * 256 + threadIdx.x) * 4;
  const float* src; int off;
  if      (i <  65536) { src = w1;   off = 0; }
  else if (i <  98304) { src = w2;   off = 65536; }
  else if (i < 100352) { src = wq;   off = 98304; }
  else if (i < 108544) { src = woff; off = 100352; }
  else if (i < 110592) { src = wk;   off = 108544; }
  else if (i < 126976) { src = wv;   off = 110592; }
  else if (i < 225280) { src = wb;   off = 126976; }
  else return;
  float4 v = *(const float4*)(src + (i - off));
  s4v o;
  o[0] = (short)f2bf(v.x); o[1] = (short)f2bf(v.y);
  o[2] = (short)f2bf(v.z); o[3] = (short)f2bf(v.w);
  *(s4v*)(dst + i) = o;
}

// ---------------------------------------------------------------------------
// K1: prep + stageA + stageB. CHANGED: 256 blocks x 512 thr, 32 px/block.
// Weight A-fragments loaded ONCE per block, reused for TWO 16-px B-tiles
// (halves the dominant per-pixel weight-load instruction stream).
// LDS overlay: hrow (phase P) aliases qf/vf (phases A/B). 55.8 KB total.
// ---------------------------------------------------------------------------
__global__ __launch_bounds__(512, 2) void k1_fused(
    const float* __restrict__ low, const float* __restrict__ high,
    const short* __restrict__ wc,
    const float* __restrict__ b1, const float* __restrict__ b2,
    const float* __restrict__ bq, const float* __restrict__ boff,
    const float* __restrict__ bk, const float* __restrict__ bv,
    short* __restrict__ xh, float* __restrict__ q_t, float* __restrict__ k_t,
    float* __restrict__ off_t, short* __restrict__ v_t) {
  __shared__ __align__(16) char smem[33280 + 22528];
  short* xin_s = (short*)smem;                   // [32][520] = 33280 B
  float* hrow_s = (float*)(smem + 33280);        // [256][2][11] = 22528 B (P)
  short* qf_s = (short*)(smem + 33280);          // [32][136] = 8704 B (A/B)
  short* vf_s = (short*)(smem + 33280 + 8704);   // [32][136]

  const int tid = threadIdx.x;
  const int wg = swizzle_wg32(blockIdx.x);
  const int pix0 = wg * 32;
  const int b = pix0 >> 12;
  const int n0 = pix0 & (NL - 1);
  const int yrow = n0 >> 6;          // 32 px live in ONE output row
  const int x0blk = n0 & 63;         // 0 or 32

  // vertical taps (uniform over the block)
  float syf = yrow * 0.5f - 0.25f;
  float y0f = floorf(syf);
  float wy = syf - y0f;
  int y0i = (int)y0f;
  int y0c = min(HH - 1, max(0, y0i)), y1c = min(HH - 1, max(0, y0i + 1));

  // ---- phase P: two 16-px subtiles, hrow LDS reused ----
  for (int tt = 0; tt < 2; tt++) {
    const int pt0 = tt * 16;
    const int xsub = x0blk + pt0;
    const int xc0 = (xsub >> 1) - 1;
    const int nsub = n0 + pt0;

    // low loads (independent of hrow; 8 px x 1 ch per thread, 2x float4)
    const int cL = tid >> 1, hL = tid & 1;
    const float* lp = low + (size_t)(b * 256 + cL) * NL + nsub + hL * 8;
    float4 lo0 = *(const float4*)(lp);
    float4 lo1 = *(const float4*)(lp + 4);

    if (tt) __syncthreads();   // prior subtile's hrow reads done
    // stage high rows: thread -> (channel tid>>1, row tid&1), 10 cols
    {
      const int c = tid >> 1, r = tid & 1;
      const int yr = r ? y1c : y0c;
      const float* src = high + ((size_t)(b * 256 + c) * HH + yr) * WH;
      float* hd = hrow_s + (c * 2 + r) * 11;
#pragma unroll
      for (int j = 0; j < 10; j++) {
        int col = min(WH - 1, max(0, xc0 + j));
        hd[j] = src[col];
      }
    }
    __syncthreads();

    // bilinear from LDS (8 ch/thread) + low from regs
    {
      const int nl = tid & 15, cg = tid >> 4;   // px-in-subtile, ch-group
      const int x = xsub + nl;
      float sxf = x * 0.5f - 0.25f;
      float x0f_ = floorf(sxf);
      float wx = sxf - x0f_;
      int x0i = (int)x0f_;
      int j0 = min(WH - 1, max(0, x0i)) - xc0;
      int j1 = min(WH - 1, max(0, x0i + 1)) - xc0;
      float w1x = 1.f - wx;
#pragma unroll
      for (int i = 0; i < 8; i++) {
        int c = cg * 8 + i;
        const float* hr = hrow_s + c * 22;
        float top = hr[j0] * w1x + hr[j1] * wx;
        float bot = hr[11 + j0] * w1x + hr[11 + j1] * wx;
        float v = top * (1.f - wy) + bot * wy;
        xin_s[(pt0 + nl) * 520 + c] = (short)f2bf(v);
      }
      // low: thread owns (cL, 8 px starting hL*8)
      float lv[8] = {lo0.x, lo0.y, lo0.z, lo0.w, lo1.x, lo1.y, lo1.z, lo1.w};
#pragma unroll
      for (int p = 0; p < 8; p++)
        xin_s[(pt0 + hL * 8 + p) * 520 + 256 + cL] = (short)f2bf(lv[p]);
    }
  }
  __syncthreads();

  // ---- store xh (high half of xin; 32 rows x 256 ch) ----
  {
    const int r = tid >> 4, c0 = (tid & 15) * 16;
    s8v v0 = *(const s8v*)(xin_s + r * 520 + c0);
    s8v v1 = *(const s8v*)(xin_s + r * 520 + c0 + 8);
    *(s8v*)(xh + (size_t)(pix0 + r) * 256 + c0) = v0;
    *(s8v*)(xh + (size_t)(pix0 + r) * 256 + c0 + 8) = v1;
  }

  const int wave = tid >> 6, lane = tid & 63;
  const int quad = lane >> 4, id = lane & 15;

  // ---- phase A1: qf = W1 @ xin, K=512; ONE weight frag, TWO B-tiles ----
  {
    f32x4 acc0 = (f32x4){0.f, 0.f, 0.f, 0.f};
    f32x4 acc1 = (f32x4){0.f, 0.f, 0.f, 0.f};
    const short* a0 = wc + (size_t)(wave * 16 + id) * 512 + quad * 8;
    const short* bp0 = xin_s + id * 520 + quad * 8;
    const short* bp1 = bp0 + 16 * 520;
#pragma unroll
    for (int kk = 0; kk < 512; kk += 32) {
      s8v af = *(const s8v*)(a0 + kk);
      acc0 = __builtin_amdgcn_mfma_f32_16x16x32_bf16(af, *(const s8v*)(bp0 + kk), acc0, 0, 0, 0);
      acc1 = __builtin_amdgcn_mfma_f32_16x16x32_bf16(af, *(const s8v*)(bp1 + kk), acc1, 0, 0, 0);
    }
    int m0 = wave * 16 + quad * 4;
    s4v o0, o1;
#pragma unroll
    for (int r = 0; r < 4; r++) {
      o0[r] = (short)f2bf(acc0[r] + b1[m0 + r]);
      o1[r] = (short)f2bf(acc1[r] + b1[m0 + r]);
    }
    *(s4v*)(qf_s + id * 136 + m0) = o0;
    *(s4v*)(qf_s + (16 + id) * 136 + m0) = o1;
  }

  // ---- phase A2: vf = W2 @ xin[:,0:256], K=256 ----
  {
    f32x4 acc0 = (f32x4){0.f, 0.f, 0.f, 0.f};
    f32x4 acc1 = (f32x4){0.f, 0.f, 0.f, 0.f};
    const short* a0 = wc + 65536 + (size_t)(wave * 16 + id) * 256 + quad * 8;
    const short* bp0 = xin_s + id * 520 + quad * 8;
    const short* bp1 = bp0 + 16 * 520;
#pragma unroll
    for (int kk = 0; kk < 256; kk += 32) {
      s8v af = *(const s8v*)(a0 + kk);
      acc0 = __builtin_amdgcn_mfma_f32_16x16x32_bf16(af, *(const s8v*)(bp0 + kk), acc0, 0, 0, 0);
      acc1 = __builtin_amdgcn_mfma_f32_16x16x32_bf16(af, *(const s8v*)(bp1 + kk), acc1, 0, 0, 0);
    }
    int m0 = wave * 16 + quad * 4;
    s4v o0, o1;
#pragma unroll
    for (int r = 0; r < 4; r++) {
      o0[r] = (short)f2bf(acc0[r] + b2[m0 + r]);
      o1[r] = (short)f2bf(acc1[r] + b2[m0 + r]);
    }
    *(s4v*)(vf_s + id * 136 + m0) = o0;
    *(s4v*)(vf_s + (16 + id) * 136 + m0) = o1;
  }
  __syncthreads();

  // ---- phase B: 14 m-frags (0:q, 1-4:off, 5:k, 6-13:v), K=128, 2 tiles ----
  for (int f = wave; f < 14; f += 8) {
    const short* ap = wc + 98304 + (size_t)(f * 16 + id) * 128 + quad * 8;
    const short* base = (f < 5 ? qf_s : vf_s);
    const short* bp0 = base + id * 136 + quad * 8;
    const short* bp1 = base + (16 + id) * 136 + quad * 8;
    f32x4 acc0 = (f32x4){0.f, 0.f, 0.f, 0.f};
    f32x4 acc1 = (f32x4){0.f, 0.f, 0.f, 0.f};
#pragma unroll
    for (int kk = 0; kk < 128; kk += 32) {
      s8v af = *(const s8v*)(ap + kk);
      acc0 = __builtin_amdgcn_mfma_f32_16x16x32_bf16(af, *(const s8v*)(bp0 + kk), acc0, 0, 0, 0);
      acc1 = __builtin_amdgcn_mfma_f32_16x16x32_bf16(af, *(const s8v*)(bp1 + kk), acc1, 0, 0, 0);
    }
    const int mq = quad * 4;
#pragma unroll
    for (int t = 0; t < 2; t++) {
      const f32x4 acc = t ? acc1 : acc0;
      const int pix = pix0 + t * 16 + id;
      if (f == 0) {
        f32x4 v;
#pragma unroll
        for (int r = 0; r < 4; r++) v[r] = acc[r] + bq[mq + r];
        *(f32x4*)(q_t + (size_t)pix * 16 + mq) = v;
      } else if (f < 5) {
        int m = (f - 1) * 16 + mq;
        f32x4 v;
#pragma unroll
        for (int r = 0; r < 4; r++) v[r] = acc[r] + boff[m + r];
        *(f32x4*)(off_t + (size_t)pix * 64 + m) = v;
      } else if (f == 5) {
        f32x4 v;
#pragma unroll
        for (int r = 0; r < 4; r++) v[r] = acc[r] + bk[mq + r];
        *(f32x4*)(k_t + (size_t)pix * 16 + mq) = v;
      } else {
        int m = (f - 6) * 16 + mq;
        s4v o;
#pragma unroll
        for (int r = 0; r < 4; r++) o[r] = (short)f2bf(acc[r] + bv[m + r]);
        *(s4v*)(v_t + (size_t)pix * 128 + m) = o;
      }
    }
  }
}

// ---------------------------------------------------------------------------
// K2: deformable attention + final GEMM (+BN+ReLU).
// CHANGED: 256 blocks x 512 thr (8 waves), 32 px/block, 4 queries/wave.
// Phase F: Wb fragments loaded once per wave, reused for TWO pixel-tiles
// (halves the Wb instruction stream). xh tile prefetched at kernel start.
// ---------------------------------------------------------------------------
__global__ __launch_bounds__(512, 2) void k2_fused(
    const float* __restrict__ q_t, const float* __restrict__ k_t,
    const short* __restrict__ v_t, const float* __restrict__ off_t,
    const short* __restrict__ xh, const short* __restrict__ wb,
    const float* __restrict__ gamma, const float* __restrict__ beta,
    const float* __restrict__ rmean, const float* __restrict__ rvar,
    float* __restrict__ out) {
  __shared__ __align__(16) char smem[32768 + 8704 + 16896];
  float2* s_wi = (float2*)smem;                    // [32][32][4] = 32 KB
  short* attn_s = (short*)(smem + 32768);          // [32][136] = 8704 B
  short* xh_s = (short*)(smem + 32768 + 8704);     // [32][264] = 16896 B

  const int tid = threadIdx.x;
  const int wave = tid >> 6, lane = tid & 63;
  const int wg = swizzle_wg32(blockIdx.x);
  const int pix0 = wg * 32;

  // ---- prefetch xh tile (consumed after the barrier; T14 split) ----
  const int sp = tid >> 4, sc = (tid & 15) * 16;
  const short* xp = xh + (size_t)(pix0 + sp) * 256 + sc;
  uint4 xr0 = *(const uint4*)(xp);
  uint4 xr1 = *(const uint4*)(xp + 8);

  // ---- phase T: attention, FOUR queries per wave (sequential) ----
  for (int qi = 0; qi < 4; qi++) {
    const int ql = wave * 4 + qi;
    const int qidx = pix0 + ql;
    const int b = qidx >> 12;
    const int n = qidx & (NL - 1);
    const int qy = n >> 6, qx = n & 63;

    const int pt = lane >> 1, h = lane & 1;
    float2 dxy = *(const float2*)(off_t + (size_t)qidx * 64 + 2 * pt);

    const float* qp = q_t + (size_t)qidx * 16;
    float qreg[16];
#pragma unroll
    for (int i = 0; i < 16; i += 4) {
      float4 t4 = *(const float4*)(qp + i);
      qreg[i] = t4.x; qreg[i + 1] = t4.y; qreg[i + 2] = t4.z; qreg[i + 3] = t4.w;
    }

    float sx = (float)qx + dxy.x;
    float sy = (float)qy + dxy.y;
    float x0f = floorf(sx), y0f = floorf(sy);
    float wx = sx - x0f, wy = sy - y0f;
    int x0i = (int)x0f, y0i = (int)y0f;
    int x0 = min(63, max(0, x0i)), x1 = min(63, max(0, x0i + 1));
    int y0 = min(63, max(0, y0i)), y1 = min(63, max(0, y0i + 1));

    int   yr  = h ? y1 : y0;
    float wyr = h ? wy : (1.f - wy);
    int   pa = yr * 64 + x0, pb = yr * 64 + x1;
    float wa = wyr * (1.f - wx), wb_ = wyr * wx;

    const float* kb = k_t + (size_t)b * NL * 16;
    float da = 0.f, db = 0.f;
    {
      const float* ka = kb + (size_t)pa * 16;
      const float* kc = kb + (size_t)pb * 16;
#pragma unroll
      for (int i = 0; i < 16; i += 4) {
        float4 a4 = *(const float4*)(ka + i);
        float4 c4 = *(const float4*)(kc + i);
        da = fmaf(qreg[i], a4.x, da); da = fmaf(qreg[i + 1], a4.y, da);
        da = fmaf(qreg[i + 2], a4.z, da); da = fmaf(qreg[i + 3], a4.w, da);
        db = fmaf(qreg[i], c4.x, db); db = fmaf(qreg[i + 1], c4.y, db);
        db = fmaf(qreg[i + 2], c4.z, db); db = fmaf(qreg[i + 3], c4.w, db);
      }
    }
    float part = wa * da + wb_ * db;
    part += __shfl_xor(part, 1, 64);
    float logit = part * 0.25f;

    // no max-reduce: logits structurally bounded; 2/ssum cancels scale.
    float e = __expf(logit);

    s_wi[(ql * 32 + pt) * 4 + 2 * h + 0] = make_float2(e * wa,  __int_as_float(pa << 7));
    s_wi[(ql * 32 + pt) * 4 + 2 * h + 1] = make_float2(e * wb_, __int_as_float(pb << 7));

    // ---- V-gather: tap-parallel, 8 channels per lane per point ----
    const int t = lane >> 4, chunk = lane & 15;
    const short* vb = v_t + (size_t)b * NL * 128 + chunk * 8;
    float o[8];
#pragma unroll
    for (int j = 0; j < 8; j++) o[j] = 0.f;
    for (int base = 0; base < 32; base += 8) {
      float w8[8]; int ix[8];
#pragma unroll
      for (int j = 0; j < 8; j++) {
        float2 wi = s_wi[(ql * 32 + base + j) * 4 + t];
        w8[j] = wi.x;
        ix[j] = __float_as_int(wi.y);
      }
      uint4 u[8];
#pragma unroll
      for (int j = 0; j < 8; j++) u[j] = *(const uint4*)(vb + ix[j]);
#pragma unroll
      for (int j = 0; j < 8; j++) {
        o[0] = fmaf(w8[j], bfbits2f(u[j].x & 0xffffu), o[0]);
        o[1] = fmaf(w8[j], bfbits2f(u[j].x >> 16),     o[1]);
        o[2] = fmaf(w8[j], bfbits2f(u[j].y & 0xffffu), o[2]);
        o[3] = fmaf(w8[j], bfbits2f(u[j].y >> 16),     o[3]);
        o[4] = fmaf(w8[j], bfbits2f(u[j].z & 0xffffu), o[4]);
        o[5] = fmaf(w8[j], bfbits2f(u[j].z >> 16),     o[5]);
        o[6] = fmaf(w8[j], bfbits2f(u[j].w & 0xffffu), o[6]);
        o[7] = fmaf(w8[j], bfbits2f(u[j].w >> 16),     o[7]);
      }
    }
    float ssum = e;
#pragma unroll
    for (int s = 32; s > 0; s >>= 1) ssum += __shfl_xor(ssum, s, 64);
    float scale = 2.f / ssum;

#pragma unroll
    for (int j = 0; j < 8; j++) {
      o[j] += __shfl_xor(o[j], 16, 64);
      o[j] += __shfl_xor(o[j], 32, 64);
    }
    if (t == 0) {
      uint4 pk;
      pk.x = (unsigned)f2bf(o[0] * scale) | ((unsigned)f2bf(o[1] * scale) << 16);
      pk.y = (unsigned)f2bf(o[2] * scale) | ((unsigned)f2bf(o[3] * scale) << 16);
      pk.z = (unsigned)f2bf(o[4] * scale) | ((unsigned)f2bf(o[5] * scale) << 16);
      pk.w = (unsigned)f2bf(o[6] * scale) | ((unsigned)f2bf(o[7] * scale) << 16);
      *(uint4*)(attn_s + ql * 136 + chunk * 8) = pk;
    }
  }
  // write the prefetched xh tile; barrier orders it for phase F
  *(uint4*)(xh_s + sp * 264 + sc) = xr0;
  *(uint4*)(xh_s + sp * 264 + sc + 8) = xr1;
  __syncthreads();

  // ---- phase F: final GEMM, 32 px, M=256; Wb frag reused for 2 tiles ----
  {
    const int quad = lane >> 4, id = lane & 15;
    const short* bs0 = attn_s + id * 136 + quad * 8;
    const short* bs1 = attn_s + (16 + id) * 136 + quad * 8;
    const short* bg0 = xh_s + id * 264 + quad * 8;
    const short* bg1 = xh_s + (16 + id) * 264 + quad * 8;
#pragma unroll
    for (int j = 0; j < 2; j++) {
      const int m0 = wave * 16 + j * 128;
      const short* ap = wb + (size_t)(m0 + id) * 384 + quad * 8;
      f32x4 acc0 = (f32x4){0.f, 0.f, 0.f, 0.f};
      f32x4 acc1 = (f32x4){0.f, 0.f, 0.f, 0.f};
#pragma unroll
      for (int k = 0; k < 4; k++) {
        s8v af = *(const s8v*)(ap + k * 32);
        acc0 = __builtin_amdgcn_mfma_f32_16x16x32_bf16(af, *(const s8v*)(bs0 + k * 32), acc0, 0, 0, 0);
        acc1 = __builtin_amdgcn_mfma_f32_16x16x32_bf16(af, *(const s8v*)(bs1 + k * 32), acc1, 0, 0, 0);
      }
#pragma unroll
      for (int k = 0; k < 8; k++) {
        s8v af = *(const s8v*)(ap + 128 + k * 32);
        acc0 = __builtin_amdgcn_mfma_f32_16x16x32_bf16(af, *(const s8v*)(bg0 + k * 32), acc0, 0, 0, 0);
        acc1 = __builtin_amdgcn_mfma_f32_16x16x32_bf16(af, *(const s8v*)(bg1 + k * 32), acc1, 0, 0, 0);
      }
      const int mbase = m0 + quad * 4;
#pragma unroll
      for (int r = 0; r < 4; r++) {
        int o = mbase + r;
        float s  = gamma[o] * rsqrtf(rvar[o] + 1e-5f);
        float sh = beta[o] - rmean[o] * s;
        {
          const int pix = pix0 + id;
          const int bb = pix >> 12, nlow = pix & (NL - 1);
          __builtin_nontemporal_store(fmaxf(fmaf(acc0[r], s, sh), 0.f),
                                      &out[((size_t)bb * 256 + o) * NL + nlow]);
        }
        {
          const int pix = pix0 + 16 + id;
          const int bb = pix >> 12, nlow = pix & (NL - 1);
          __builtin_nontemporal_store(fmaxf(fmaf(acc1[r], s, sh), 0.f),
                                      &out[((size_t)bb * 256 + o) * NL + nlow]);
        }
      }
    }
  }
}

// ---------------------------------------------------------------------------
extern "C" void kernel_launch(void* const* d_in, const int* in_sizes, int n_in,
                              void* d_out, int out_size, void* d_ws, size_t ws_size,
                              hipStream_t stream) {
  const float* low   = (const float*)d_in[0];
  const float* high  = (const float*)d_in[1];
  const float* W1    = (const float*)d_in[2];
  const float* b1    = (const float*)d_in[3];
  const float* W2    = (const float*)d_in[4];
  const float* b2    = (const float*)d_in[5];
  const float* Wq    = (const float*)d_in[6];
  const float* bq    = (const float*)d_in[7];
  const float* Wk    = (const float*)d_in[8];
  const float* bk    = (const float*)d_in[9];
  const float* Wv    = (const float*)d_in[10];
  const float* bv    = (const float*)d_in[11];
  const float* Woff  = (const float*)d_in[12];
  const float* boff  = (const float*)d_in[13];
  const float* Wb    = (const float*)d_in[14];
  const float* gamma = (const float*)d_in[15];
  const float* beta  = (const float*)d_in[16];
  const float* rmean = (const float*)d_in[17];
  const float* rvar  = (const float*)d_in[18];
  float* out = (float*)d_out;

  short* ws    = (short*)d_ws;
  short* xh    = ws;                    // [8192][256] bf16 = 2,097,152 sh
  short* v_t   = xh + 2097152;          // [8192][128] bf16
  short* wc    = v_t + 1048576;         // 225,280 bf16
  float* q_t   = (float*)(wc + 225280); // [8192][16] f32
  float* k_t   = q_t + 131072;          // [8192][16] f32
  float* off_t = k_t + 131072;          // [8192][64] f32

  convert_weights_k<<<220, 256, 0, stream>>>(W1, W2, Wq, Woff, Wk, Wv, Wb, wc);
  k1_fused<<<256, 512, 0, stream>>>(low, high, wc, b1, b2, bq, boff, bk, bv,
                                    xh, q_t, k_t, off_t, v_t);
  k2_fused<<<256, 512, 0, stream>>>(q_t, k_t, v_t, off_t, xh, wc + 126976,
                                    gamma, beta, rmean, rvar, out);
}

// Round 9
// 136.803 us; speedup vs baseline: 1.2547x; 1.0015x over previous
//
#include <hip/hip_runtime.h>
#include <hip/hip_bf16.h>

#define NL 4096   // 64*64 low-res pixels
#define HH 32
#define WH 32

typedef __attribute__((ext_vector_type(8))) short s8v;   // 8 bf16 MFMA A/B frag
typedef __attribute__((ext_vector_type(4))) short s4v;   // 4 bf16 (8B)
typedef __attribute__((ext_vector_type(4))) float f32x4; // MFMA C/D frag

static __device__ inline unsigned short f2bf(float x) {
  __hip_bfloat16 h = __float2bfloat16(x);   // RNE
  return *reinterpret_cast<unsigned short*>(&h);
}
static __device__ inline float bfbits2f(unsigned int lo16) {
  unsigned int u = lo16 << 16;
  return *reinterpret_cast<float*>(&u);
}
static __device__ inline void acc8(float* o, float w, uint4 u) {
  o[0] = fmaf(w, bfbits2f(u.x & 0xffffu), o[0]);
  o[1] = fmaf(w, bfbits2f(u.x >> 16),     o[1]);
  o[2] = fmaf(w, bfbits2f(u.y & 0xffffu), o[2]);
  o[3] = fmaf(w, bfbits2f(u.y >> 16),     o[3]);
  o[4] = fmaf(w, bfbits2f(u.z & 0xffffu), o[4]);
  o[5] = fmaf(w, bfbits2f(u.z >> 16),     o[5]);
  o[6] = fmaf(w, bfbits2f(u.w & 0xffffu), o[6]);
  o[7] = fmaf(w, bfbits2f(u.w >> 16),     o[7]);
}
// 256 blocks, 8 XCDs: bijective, contiguous 32-block band per XCD
static __device__ inline int swizzle_wg32(int b) {
  return ((b & 7) << 5) | (b >> 3);
}

// ---------------------------------------------------------------------------
// Weight fp32 -> bf16, packed (4 elems/thread):
//   [0,65536) W1 | [65536,98304) W2 | [98304,100352) Wq | [100352,108544) Woff
//   [108544,110592) Wk | [110592,126976) Wv | [126976,225280) Wb
// ---------------------------------------------------------------------------
__global__ __launch_bounds__(256) void convert_weights_k(
    const float* __restrict__ w1, const float* __restrict__ w2,
    const float* __restrict__ wq, const float* __restrict__ woff,
    const float* __restrict__ wk, const float* __restrict__ wv,
    const float* __restrict__ wb, short* __restrict__ dst) {
  int i = (blockIdx.x * 256 + threadIdx.x) * 4;
  const float* src; int off;
  if      (i <  65536) { src = w1;   off = 0; }
  else if (i <  98304) { src = w2;   off = 65536; }
  else if (i < 100352) { src = wq;   off = 98304; }
  else if (i < 108544) { src = woff; off = 100352; }
  else if (i < 110592) { src = wk;   off = 108544; }
  else if (i < 126976) { src = wv;   off = 110592; }
  else if (i < 225280) { src = wb;   off = 126976; }
  else return;
  float4 v = *(const float4*)(src + (i - off));
  s4v o;
  o[0] = (short)f2bf(v.x); o[1] = (short)f2bf(v.y);
  o[2] = (short)f2bf(v.z); o[3] = (short)f2bf(v.w);
  *(s4v*)(dst + i) = o;
}

// ---------------------------------------------------------------------------
// K1: prep + stageA + stageB. 256 blocks x 512 thr, 32 px/block.
// Weight A-fragments loaded ONCE per block, reused for TWO 16-px B-tiles.
// (unchanged from round 8 — it delivered the win)
// ---------------------------------------------------------------------------
__global__ __launch_bounds__(512, 2) void k1_fused(
    const float* __restrict__ low, const float* __restrict__ high,
    const short* __restrict__ wc,
    const float* __restrict__ b1, const float* __restrict__ b2,
    const float* __restrict__ bq, const float* __restrict__ boff,
    const float* __restrict__ bk, const float* __restrict__ bv,
    short* __restrict__ xh, float* __restrict__ q_t, float* __restrict__ k_t,
    float* __restrict__ off_t, short* __restrict__ v_t) {
  __shared__ __align__(16) char smem[33280 + 22528];
  short* xin_s = (short*)smem;                   // [32][520] = 33280 B
  float* hrow_s = (float*)(smem + 33280);        // [256][2][11] = 22528 B (P)
  short* qf_s = (short*)(smem + 33280);          // [32][136] = 8704 B (A/B)
  short* vf_s = (short*)(smem + 33280 + 8704);   // [32][136]

  const int tid = threadIdx.x;
  const int wg = swizzle_wg32(blockIdx.x);
  const int pix0 = wg * 32;
  const int b = pix0 >> 12;
  const int n0 = pix0 & (NL - 1);
  const int yrow = n0 >> 6;          // 32 px live in ONE output row
  const int x0blk = n0 & 63;         // 0 or 32

  // vertical taps (uniform over the block)
  float syf = yrow * 0.5f - 0.25f;
  float y0f = floorf(syf);
  float wy = syf - y0f;
  int y0i = (int)y0f;
  int y0c = min(HH - 1, max(0, y0i)), y1c = min(HH - 1, max(0, y0i + 1));

  // ---- phase P: two 16-px subtiles, hrow LDS reused ----
  for (int tt = 0; tt < 2; tt++) {
    const int pt0 = tt * 16;
    const int xsub = x0blk + pt0;
    const int xc0 = (xsub >> 1) - 1;
    const int nsub = n0 + pt0;

    // low loads (independent of hrow; 8 px x 1 ch per thread, 2x float4)
    const int cL = tid >> 1, hL = tid & 1;
    const float* lp = low + (size_t)(b * 256 + cL) * NL + nsub + hL * 8;
    float4 lo0 = *(const float4*)(lp);
    float4 lo1 = *(const float4*)(lp + 4);

    if (tt) __syncthreads();   // prior subtile's hrow reads done
    // stage high rows: thread -> (channel tid>>1, row tid&1), 10 cols
    {
      const int c = tid >> 1, r = tid & 1;
      const int yr = r ? y1c : y0c;
      const float* src = high + ((size_t)(b * 256 + c) * HH + yr) * WH;
      float* hd = hrow_s + (c * 2 + r) * 11;
#pragma unroll
      for (int j = 0; j < 10; j++) {
        int col = min(WH - 1, max(0, xc0 + j));
        hd[j] = src[col];
      }
    }
    __syncthreads();

    // bilinear from LDS (8 ch/thread) + low from regs
    {
      const int nl = tid & 15, cg = tid >> 4;   // px-in-subtile, ch-group
      const int x = xsub + nl;
      float sxf = x * 0.5f - 0.25f;
      float x0f_ = floorf(sxf);
      float wx = sxf - x0f_;
      int x0i = (int)x0f_;
      int j0 = min(WH - 1, max(0, x0i)) - xc0;
      int j1 = min(WH - 1, max(0, x0i + 1)) - xc0;
      float w1x = 1.f - wx;
#pragma unroll
      for (int i = 0; i < 8; i++) {
        int c = cg * 8 + i;
        const float* hr = hrow_s + c * 22;
        float top = hr[j0] * w1x + hr[j1] * wx;
        float bot = hr[11 + j0] * w1x + hr[11 + j1] * wx;
        float v = top * (1.f - wy) + bot * wy;
        xin_s[(pt0 + nl) * 520 + c] = (short)f2bf(v);
      }
      // low: thread owns (cL, 8 px starting hL*8)
      float lv[8] = {lo0.x, lo0.y, lo0.z, lo0.w, lo1.x, lo1.y, lo1.z, lo1.w};
#pragma unroll
      for (int p = 0; p < 8; p++)
        xin_s[(pt0 + hL * 8 + p) * 520 + 256 + cL] = (short)f2bf(lv[p]);
    }
  }
  __syncthreads();

  // ---- store xh (high half of xin; 32 rows x 256 ch) ----
  {
    const int r = tid >> 4, c0 = (tid & 15) * 16;
    s8v v0 = *(const s8v*)(xin_s + r * 520 + c0);
    s8v v1 = *(const s8v*)(xin_s + r * 520 + c0 + 8);
    *(s8v*)(xh + (size_t)(pix0 + r) * 256 + c0) = v0;
    *(s8v*)(xh + (size_t)(pix0 + r) * 256 + c0 + 8) = v1;
  }

  const int wave = tid >> 6, lane = tid & 63;
  const int quad = lane >> 4, id = lane & 15;

  // ---- phase A1: qf = W1 @ xin, K=512; ONE weight frag, TWO B-tiles ----
  {
    f32x4 acc0 = (f32x4){0.f, 0.f, 0.f, 0.f};
    f32x4 acc1 = (f32x4){0.f, 0.f, 0.f, 0.f};
    const short* a0 = wc + (size_t)(wave * 16 + id) * 512 + quad * 8;
    const short* bp0 = xin_s + id * 520 + quad * 8;
    const short* bp1 = bp0 + 16 * 520;
#pragma unroll
    for (int kk = 0; kk < 512; kk += 32) {
      s8v af = *(const s8v*)(a0 + kk);
      acc0 = __builtin_amdgcn_mfma_f32_16x16x32_bf16(af, *(const s8v*)(bp0 + kk), acc0, 0, 0, 0);
      acc1 = __builtin_amdgcn_mfma_f32_16x16x32_bf16(af, *(const s8v*)(bp1 + kk), acc1, 0, 0, 0);
    }
    int m0 = wave * 16 + quad * 4;
    s4v o0, o1;
#pragma unroll
    for (int r = 0; r < 4; r++) {
      o0[r] = (short)f2bf(acc0[r] + b1[m0 + r]);
      o1[r] = (short)f2bf(acc1[r] + b1[m0 + r]);
    }
    *(s4v*)(qf_s + id * 136 + m0) = o0;
    *(s4v*)(qf_s + (16 + id) * 136 + m0) = o1;
  }

  // ---- phase A2: vf = W2 @ xin[:,0:256], K=256 ----
  {
    f32x4 acc0 = (f32x4){0.f, 0.f, 0.f, 0.f};
    f32x4 acc1 = (f32x4){0.f, 0.f, 0.f, 0.f};
    const short* a0 = wc + 65536 + (size_t)(wave * 16 + id) * 256 + quad * 8;
    const short* bp0 = xin_s + id * 520 + quad * 8;
    const short* bp1 = bp0 + 16 * 520;
#pragma unroll
    for (int kk = 0; kk < 256; kk += 32) {
      s8v af = *(const s8v*)(a0 + kk);
      acc0 = __builtin_amdgcn_mfma_f32_16x16x32_bf16(af, *(const s8v*)(bp0 + kk), acc0, 0, 0, 0);
      acc1 = __builtin_amdgcn_mfma_f32_16x16x32_bf16(af, *(const s8v*)(bp1 + kk), acc1, 0, 0, 0);
    }
    int m0 = wave * 16 + quad * 4;
    s4v o0, o1;
#pragma unroll
    for (int r = 0; r < 4; r++) {
      o0[r] = (short)f2bf(acc0[r] + b2[m0 + r]);
      o1[r] = (short)f2bf(acc1[r] + b2[m0 + r]);
    }
    *(s4v*)(vf_s + id * 136 + m0) = o0;
    *(s4v*)(vf_s + (16 + id) * 136 + m0) = o1;
  }
  __syncthreads();

  // ---- phase B: 14 m-frags (0:q, 1-4:off, 5:k, 6-13:v), K=128, 2 tiles ----
  for (int f = wave; f < 14; f += 8) {
    const short* ap = wc + 98304 + (size_t)(f * 16 + id) * 128 + quad * 8;
    const short* base = (f < 5 ? qf_s : vf_s);
    const short* bp0 = base + id * 136 + quad * 8;
    const short* bp1 = base + (16 + id) * 136 + quad * 8;
    f32x4 acc0 = (f32x4){0.f, 0.f, 0.f, 0.f};
    f32x4 acc1 = (f32x4){0.f, 0.f, 0.f, 0.f};
#pragma unroll
    for (int kk = 0; kk < 128; kk += 32) {
      s8v af = *(const s8v*)(ap + kk);
      acc0 = __builtin_amdgcn_mfma_f32_16x16x32_bf16(af, *(const s8v*)(bp0 + kk), acc0, 0, 0, 0);
      acc1 = __builtin_amdgcn_mfma_f32_16x16x32_bf16(af, *(const s8v*)(bp1 + kk), acc1, 0, 0, 0);
    }
    const int mq = quad * 4;
#pragma unroll
    for (int t = 0; t < 2; t++) {
      const f32x4 acc = t ? acc1 : acc0;
      const int pix = pix0 + t * 16 + id;
      if (f == 0) {
        f32x4 v;
#pragma unroll
        for (int r = 0; r < 4; r++) v[r] = acc[r] + bq[mq + r];
        *(f32x4*)(q_t + (size_t)pix * 16 + mq) = v;
      } else if (f < 5) {
        int m = (f - 1) * 16 + mq;
        f32x4 v;
#pragma unroll
        for (int r = 0; r < 4; r++) v[r] = acc[r] + boff[m + r];
        *(f32x4*)(off_t + (size_t)pix * 64 + m) = v;
      } else if (f == 5) {
        f32x4 v;
#pragma unroll
        for (int r = 0; r < 4; r++) v[r] = acc[r] + bk[mq + r];
        *(f32x4*)(k_t + (size_t)pix * 16 + mq) = v;
      } else {
        int m = (f - 6) * 16 + mq;
        s4v o;
#pragma unroll
        for (int r = 0; r < 4; r++) o[r] = (short)f2bf(acc[r] + bv[m + r]);
        *(s4v*)(v_t + (size_t)pix * 128 + m) = o;
      }
    }
  }
}

// ---------------------------------------------------------------------------
// K2: deformable attention + final GEMM (+BN+ReLU).
// 256 blocks x 512 thr (8 waves), 32 px/block, 4 queries/wave.
// CHANGED: queries processed in PAIRS with interleaved gathers — two
// independent {table-read -> L2-load -> fma} chains per wave (4-deep each,
// 8 loads in flight) so q0's latency hides under q1's issue/compute.
// lb(512,4): VGPR<=128 keeps the in-flight set live AND 2 blocks/CU.
// ---------------------------------------------------------------------------
__global__ __launch_bounds__(512, 4) void k2_fused(
    const float* __restrict__ q_t, const float* __restrict__ k_t,
    const short* __restrict__ v_t, const float* __restrict__ off_t,
    const short* __restrict__ xh, const short* __restrict__ wb,
    const float* __restrict__ gamma, const float* __restrict__ beta,
    const float* __restrict__ rmean, const float* __restrict__ rvar,
    float* __restrict__ out) {
  __shared__ __align__(16) char smem[32768 + 8704 + 16896];
  float2* s_wi = (float2*)smem;                    // [32][32][4] = 32 KB
  short* attn_s = (short*)(smem + 32768);          // [32][136] = 8704 B
  short* xh_s = (short*)(smem + 32768 + 8704);     // [32][264] = 16896 B

  const int tid = threadIdx.x;
  const int wave = tid >> 6, lane = tid & 63;
  const int wg = swizzle_wg32(blockIdx.x);
  const int pix0 = wg * 32;
  const int b = pix0 >> 12;          // whole block in one batch (32 | 4096)

  // ---- prefetch xh tile (consumed after the barrier; T14 split) ----
  const int sp = tid >> 4, sc = (tid & 15) * 16;
  const short* xp = xh + (size_t)(pix0 + sp) * 256 + sc;
  uint4 xr0 = *(const uint4*)(xp);
  uint4 xr1 = *(const uint4*)(xp + 8);

  const int pt = lane >> 1, h = lane & 1;
  const int t = lane >> 4, chunk = lane & 15;
  const short* vb = v_t + (size_t)b * NL * 128 + chunk * 8;

  // ---- phase T: attention, 2 PAIRS of queries per wave ----
  for (int qp = 0; qp < 2; qp++) {
    const int ql0 = wave * 4 + qp * 2;
    float e_q[2];

    // -- logits + weight/idx tables for both queries of the pair --
#pragma unroll
    for (int qi = 0; qi < 2; qi++) {
      const int ql = ql0 + qi;
      const int qidx = pix0 + ql;
      const int n = qidx & (NL - 1);
      const int qy = n >> 6, qx = n & 63;

      float2 dxy = *(const float2*)(off_t + (size_t)qidx * 64 + 2 * pt);

      const float* qp_ = q_t + (size_t)qidx * 16;
      float qreg[16];
#pragma unroll
      for (int i = 0; i < 16; i += 4) {
        float4 t4 = *(const float4*)(qp_ + i);
        qreg[i] = t4.x; qreg[i + 1] = t4.y; qreg[i + 2] = t4.z; qreg[i + 3] = t4.w;
      }

      float sx = (float)qx + dxy.x;
      float sy = (float)qy + dxy.y;
      float x0f = floorf(sx), y0f = floorf(sy);
      float wx = sx - x0f, wy = sy - y0f;
      int x0i = (int)x0f, y0i = (int)y0f;
      int x0 = min(63, max(0, x0i)), x1 = min(63, max(0, x0i + 1));
      int y0 = min(63, max(0, y0i)), y1 = min(63, max(0, y0i + 1));

      int   yr  = h ? y1 : y0;
      float wyr = h ? wy : (1.f - wy);
      int   pa = yr * 64 + x0, pb = yr * 64 + x1;
      float wa = wyr * (1.f - wx), wb_ = wyr * wx;

      const float* kb = k_t + (size_t)b * NL * 16;
      float da = 0.f, db = 0.f;
      {
        const float* ka = kb + (size_t)pa * 16;
        const float* kc = kb + (size_t)pb * 16;
#pragma unroll
        for (int i = 0; i < 16; i += 4) {
          float4 a4 = *(const float4*)(ka + i);
          float4 c4 = *(const float4*)(kc + i);
          da = fmaf(qreg[i], a4.x, da); da = fmaf(qreg[i + 1], a4.y, da);
          da = fmaf(qreg[i + 2], a4.z, da); da = fmaf(qreg[i + 3], a4.w, da);
          db = fmaf(qreg[i], c4.x, db); db = fmaf(qreg[i + 1], c4.y, db);
          db = fmaf(qreg[i + 2], c4.z, db); db = fmaf(qreg[i + 3], c4.w, db);
        }
      }
      float part = wa * da + wb_ * db;
      part += __shfl_xor(part, 1, 64);
      float logit = part * 0.25f;

      // no max-reduce: logits structurally bounded; 2/ssum cancels scale.
      float e = __expf(logit);
      e_q[qi] = e;

      s_wi[(ql * 32 + pt) * 4 + 2 * h + 0] = make_float2(e * wa,  __int_as_float(pa << 7));
      s_wi[(ql * 32 + pt) * 4 + 2 * h + 1] = make_float2(e * wb_, __int_as_float(pb << 7));
    }

    // -- fused dual gather: two independent 4-deep chains --
    float o0[8], o1[8];
#pragma unroll
    for (int j = 0; j < 8; j++) { o0[j] = 0.f; o1[j] = 0.f; }
    for (int base = 0; base < 32; base += 4) {
      float w0[4], w1[4]; int i0[4], i1[4];
#pragma unroll
      for (int j = 0; j < 4; j++) {
        float2 a = s_wi[((ql0 + 0) * 32 + base + j) * 4 + t];
        float2 c = s_wi[((ql0 + 1) * 32 + base + j) * 4 + t];
        w0[j] = a.x; i0[j] = __float_as_int(a.y);
        w1[j] = c.x; i1[j] = __float_as_int(c.y);
      }
      uint4 u0[4], u1[4];
#pragma unroll
      for (int j = 0; j < 4; j++) {
        u0[j] = *(const uint4*)(vb + i0[j]);
        u1[j] = *(const uint4*)(vb + i1[j]);
      }
#pragma unroll
      for (int j = 0; j < 4; j++) {
        acc8(o0, w0[j], u0[j]);
        acc8(o1, w1[j], u1[j]);
      }
    }

    // -- deferred denominators (overlap gather tail) --
    float s0 = e_q[0], s1 = e_q[1];
#pragma unroll
    for (int s = 32; s > 0; s >>= 1) {
      s0 += __shfl_xor(s0, s, 64);
      s1 += __shfl_xor(s1, s, 64);
    }
    float sc0 = 2.f / s0, sc1 = 2.f / s1;

    // -- reduce across tap groups, write both queries --
#pragma unroll
    for (int j = 0; j < 8; j++) {
      o0[j] += __shfl_xor(o0[j], 16, 64);
      o0[j] += __shfl_xor(o0[j], 32, 64);
      o1[j] += __shfl_xor(o1[j], 16, 64);
      o1[j] += __shfl_xor(o1[j], 32, 64);
    }
    if (t == 0) {
      uint4 pk;
      pk.x = (unsigned)f2bf(o0[0] * sc0) | ((unsigned)f2bf(o0[1] * sc0) << 16);
      pk.y = (unsigned)f2bf(o0[2] * sc0) | ((unsigned)f2bf(o0[3] * sc0) << 16);
      pk.z = (unsigned)f2bf(o0[4] * sc0) | ((unsigned)f2bf(o0[5] * sc0) << 16);
      pk.w = (unsigned)f2bf(o0[6] * sc0) | ((unsigned)f2bf(o0[7] * sc0) << 16);
      *(uint4*)(attn_s + (ql0 + 0) * 136 + chunk * 8) = pk;
      pk.x = (unsigned)f2bf(o1[0] * sc1) | ((unsigned)f2bf(o1[1] * sc1) << 16);
      pk.y = (unsigned)f2bf(o1[2] * sc1) | ((unsigned)f2bf(o1[3] * sc1) << 16);
      pk.z = (unsigned)f2bf(o1[4] * sc1) | ((unsigned)f2bf(o1[5] * sc1) << 16);
      pk.w = (unsigned)f2bf(o1[6] * sc1) | ((unsigned)f2bf(o1[7] * sc1) << 16);
      *(uint4*)(attn_s + (ql0 + 1) * 136 + chunk * 8) = pk;
    }
  }
  // write the prefetched xh tile; barrier orders it for phase F
  *(uint4*)(xh_s + sp * 264 + sc) = xr0;
  *(uint4*)(xh_s + sp * 264 + sc + 8) = xr1;
  __syncthreads();

  // ---- phase F: final GEMM, 32 px, M=256; Wb frag reused for 2 tiles ----
  {
    const int quad = lane >> 4, id = lane & 15;
    const short* bs0 = attn_s + id * 136 + quad * 8;
    const short* bs1 = attn_s + (16 + id) * 136 + quad * 8;
    const short* bg0 = xh_s + id * 264 + quad * 8;
    const short* bg1 = xh_s + (16 + id) * 264 + quad * 8;
#pragma unroll
    for (int j = 0; j < 2; j++) {
      const int m0 = wave * 16 + j * 128;
      const short* ap = wb + (size_t)(m0 + id) * 384 + quad * 8;
      f32x4 acc0 = (f32x4){0.f, 0.f, 0.f, 0.f};
      f32x4 acc1 = (f32x4){0.f, 0.f, 0.f, 0.f};
#pragma unroll
      for (int k = 0; k < 4; k++) {
        s8v af = *(const s8v*)(ap + k * 32);
        acc0 = __builtin_amdgcn_mfma_f32_16x16x32_bf16(af, *(const s8v*)(bs0 + k * 32), acc0, 0, 0, 0);
        acc1 = __builtin_amdgcn_mfma_f32_16x16x32_bf16(af, *(const s8v*)(bs1 + k * 32), acc1, 0, 0, 0);
      }
#pragma unroll
      for (int k = 0; k < 8; k++) {
        s8v af = *(const s8v*)(ap + 128 + k * 32);
        acc0 = __builtin_amdgcn_mfma_f32_16x16x32_bf16(af, *(const s8v*)(bg0 + k * 32), acc0, 0, 0, 0);
        acc1 = __builtin_amdgcn_mfma_f32_16x16x32_bf16(af, *(const s8v*)(bg1 + k * 32), acc1, 0, 0, 0);
      }
      const int mbase = m0 + quad * 4;
#pragma unroll
      for (int r = 0; r < 4; r++) {
        int o = mbase + r;
        float s  = gamma[o] * rsqrtf(rvar[o] + 1e-5f);
        float sh = beta[o] - rmean[o] * s;
        {
          const int pix = pix0 + id;
          const int bb = pix >> 12, nlow = pix & (NL - 1);
          __builtin_nontemporal_store(fmaxf(fmaf(acc0[r], s, sh), 0.f),
                                      &out[((size_t)bb * 256 + o) * NL + nlow]);
        }
        {
          const int pix = pix0 + 16 + id;
          const int bb = pix >> 12, nlow = pix & (NL - 1);
          __builtin_nontemporal_store(fmaxf(fmaf(acc1[r], s, sh), 0.f),
                                      &out[((size_t)bb * 256 + o) * NL + nlow]);
        }
      }
    }
  }
}

// ---------------------------------------------------------------------------
extern "C" void kernel_launch(void* const* d_in, const int* in_sizes, int n_in,
                              void* d_out, int out_size, void* d_ws, size_t ws_size,
                              hipStream_t stream) {
  const float* low   = (const float*)d_in[0];
  const float* high  = (const float*)d_in[1];
  const float* W1    = (const float*)d_in[2];
  const float* b1    = (const float*)d_in[3];
  const float* W2    = (const float*)d_in[4];
  const float* b2    = (const float*)d_in[5];
  const float* Wq    = (const float*)d_in[6];
  const float* bq    = (const float*)d_in[7];
  const float* Wk    = (const float*)d_in[8];
  const float* bk    = (const float*)d_in[9];
  const float* Wv    = (const float*)d_in[10];
  const float* bv    = (const float*)d_in[11];
  const float* Woff  = (const float*)d_in[12];
  const float* boff  = (const float*)d_in[13];
  const float* Wb    = (const float*)d_in[14];
  const float* gamma = (const float*)d_in[15];
  const float* beta  = (const float*)d_in[16];
  const float* rmean = (const float*)d_in[17];
  const float* rvar  = (const float*)d_in[18];
  float* out = (float*)d_out;

  short* ws    = (short*)d_ws;
  short* xh    = ws;                    // [8192][256] bf16 = 2,097,152 sh
  short* v_t   = xh + 2097152;          // [8192][128] bf16
  short* wc    = v_t + 1048576;         // 225,280 bf16
  float* q_t   = (float*)(wc + 225280); // [8192][16] f32
  float* k_t   = q_t + 131072;          // [8192][16] f32
  float* off_t = k_t + 131072;          // [8192][64] f32

  convert_weights_k<<<220, 256, 0, stream>>>(W1, W2, Wq, Woff, Wk, Wv, Wb, wc);
  k1_fused<<<256, 512, 0, stream>>>(low, high, wc, b1, b2, bq, boff, bk, bv,
                                    xh, q_t, k_t, off_t, v_t);
  k2_fused<<<256, 512, 0, stream>>>(q_t, k_t, v_t, off_t, xh, wc + 126976,
                                    gamma, beta, rmean, rvar, out);
}